// Round 1
// baseline (3573.578 us; speedup 1.0000x reference)
//
#include <hip/hip_runtime.h>
#include <cmath>

#define BATCH 8
#define SEQLEN 4096
#define DMODEL 192
#define DINNER 384
#define DSTATE 16
#define DTRANK 12
#define XDBL 44            // DT_RANK + 2*D_STATE
#define MTOT (BATCH*SEQLEN)

__device__ __forceinline__ float silu_f(float x) { return x / (1.f + __expf(-x)); }

// C[M][N] = A[M][K] @ W[N][K]^T   (both operands K-contiguous, torch-style weights)
// 64x64 tile, 256 threads, 4x4 micro-tile per thread. fp32 VALU.
template<int K>
__global__ __launch_bounds__(256) void gemm_rt(const float* __restrict__ A,
                                               const float* __restrict__ W,
                                               float* __restrict__ C, int N) {
  constexpr int BM = 64, BK = 16, PAD = 68;   // PAD=68 -> <=2-way LDS conflicts
  __shared__ float As[BK * PAD];
  __shared__ float Ws[BK * PAD];
  const int tid = threadIdx.x;
  const int m0 = blockIdx.y * BM, n0 = blockIdx.x * 64;
  const int lk = (tid & 3) * 4;   // k offset of this thread's float4
  const int lm = tid >> 2;        // row 0..63
  const int tx = tid & 15, ty = tid >> 4;
  float acc[4][4] = {};
  for (int k0 = 0; k0 < K; k0 += BK) {
    float4 av = *(const float4*)(A + (size_t)(m0 + lm) * K + (k0 + lk));
    float4 wv = *(const float4*)(W + (size_t)(n0 + lm) * K + (k0 + lk));
    __syncthreads();
    As[(lk + 0) * PAD + lm] = av.x; As[(lk + 1) * PAD + lm] = av.y;
    As[(lk + 2) * PAD + lm] = av.z; As[(lk + 3) * PAD + lm] = av.w;
    Ws[(lk + 0) * PAD + lm] = wv.x; Ws[(lk + 1) * PAD + lm] = wv.y;
    Ws[(lk + 2) * PAD + lm] = wv.z; Ws[(lk + 3) * PAD + lm] = wv.w;
    __syncthreads();
#pragma unroll
    for (int kk = 0; kk < BK; kk++) {
      float4 a = *(const float4*)&As[kk * PAD + ty * 4];
      float4 b = *(const float4*)&Ws[kk * PAD + tx * 4];
      float ar[4] = {a.x, a.y, a.z, a.w}, br[4] = {b.x, b.y, b.z, b.w};
#pragma unroll
      for (int i = 0; i < 4; i++)
#pragma unroll
        for (int j = 0; j < 4; j++)
          acc[i][j] = fmaf(ar[i], br[j], acc[i][j]);
    }
  }
#pragma unroll
  for (int i = 0; i < 4; i++) {
    float4 o = make_float4(acc[i][0], acc[i][1], acc[i][2], acc[i][3]);
    *(float4*)(C + (size_t)(m0 + ty * 4 + i) * N + (n0 + tx * 4)) = o;
  }
}

// depthwise conv (k=3, same-pad, cross-correlation like jax.lax.conv) + SiLU
__global__ __launch_bounds__(256) void conv_silu_k(const float* __restrict__ xz,
                                                   const float* __restrict__ cw,
                                                   const float* __restrict__ cb,
                                                   float* __restrict__ u) {
  const int idx = blockIdx.x * 256 + threadIdx.x;   // m*DINNER + d
  const int d = idx % DINNER;
  const int m = idx / DINNER;
  const int l = m % SEQLEN;
  const float w0 = cw[d * 3 + 0], w1 = cw[d * 3 + 1], w2 = cw[d * 3 + 2];
  float s = cb[d] + w1 * xz[(size_t)m * 768 + d];
  if (l > 0)          s += w0 * xz[(size_t)(m - 1) * 768 + d];
  if (l < SEQLEN - 1) s += w2 * xz[(size_t)(m + 1) * 768 + d];
  u[idx] = silu_f(s);
}

// x_dbl[M][44] = u[M][384] @ x_proj_w[44][384]^T   (skinny GEMM, LDS-stage rows)
__global__ __launch_bounds__(256) void xproj_k(const float* __restrict__ u,
                                               const float* __restrict__ xw,
                                               float* __restrict__ xdbl) {
  __shared__ float Us[64 * 388];    // stride 388 -> 2-way conflicts max
  const int tid = threadIdx.x;
  const size_t m0 = (size_t)blockIdx.x * 64;
  for (int i = tid; i < 64 * 96; i += 256) {        // 96 float4 per row
    const int r = i / 96, c = (i % 96) * 4;
    float4 v = *(const float4*)(u + (m0 + r) * DINNER + c);
    float* dst = &Us[r * 388 + c];
    dst[0] = v.x; dst[1] = v.y; dst[2] = v.z; dst[3] = v.w;
  }
  __syncthreads();
  const int r = tid >> 2, ng = tid & 3;
  const float* urow = &Us[r * 388];
  for (int n = ng; n < XDBL; n += 4) {
    const float* wr = xw + (size_t)n * DINNER;
    float s = 0.f;
#pragma unroll 4
    for (int k = 0; k < DINNER; k += 4) {
      float4 uu = *(const float4*)(urow + k);
      float4 ww = *(const float4*)(wr + k);
      s = fmaf(uu.x, ww.x, s); s = fmaf(uu.y, ww.y, s);
      s = fmaf(uu.z, ww.z, s); s = fmaf(uu.w, ww.w, s);
    }
    xdbl[(m0 + r) * XDBL + n] = s;
  }
}

// dt[M][384] = softplus(x_dbl[:, :12] @ dt_proj_w^T + 2*dt_proj_b)  (ref adds bias twice)
__global__ __launch_bounds__(256) void dtproj_k(const float* __restrict__ xdbl,
                                                const float* __restrict__ dtw,
                                                const float* __restrict__ dtb,
                                                float* __restrict__ dt) {
  const int idx = blockIdx.x * 256 + threadIdx.x;   // m*DINNER + d
  const int d = idx % DINNER;
  const size_t m = idx / DINNER;
  const float* xr = xdbl + m * XDBL;
  const float* wr = dtw + d * DTRANK;
  float s = 2.f * dtb[d];
#pragma unroll
  for (int r = 0; r < DTRANK; r++) s = fmaf(xr[r], wr[r], s);
  dt[idx] = (s > 20.f) ? s : log1pf(__expf(s));
}

// selective scan: thread per (b, d, n). 16-lane shfl reduce for y. Gate with silu(z).
// Writes y over u in place (each u element owned by exactly one wave, read-before-write).
__global__ __launch_bounds__(256) void scan_k(const float* __restrict__ dt,
                                              const float* __restrict__ u,
                                              const float* __restrict__ xdbl,
                                              const float* __restrict__ A_log,
                                              const float* __restrict__ Dsk,
                                              const float* __restrict__ xz,
                                              float* __restrict__ yg) {
  const int tid = threadIdx.x;
  const int n = tid & 15, dd = tid >> 4;
  const int d = blockIdx.x * 16 + dd;
  const int b = blockIdx.y;
  const float Av = -expf(A_log[d * DSTATE + n]);
  const float Dv = Dsk[d];
  float h = 0.f;
  for (int l = 0; l < SEQLEN; l++) {
    const size_t m = (size_t)b * SEQLEN + l;
    const float dtv = dt[m * DINNER + d];
    const float uv  = u[m * DINNER + d];
    const float Bv  = xdbl[m * XDBL + DTRANK + n];
    const float Cv  = xdbl[m * XDBL + DTRANK + DSTATE + n];
    h = fmaf(__expf(dtv * Av), h, dtv * uv * Bv);
    float p = h * Cv;
    p += __shfl_xor(p, 1); p += __shfl_xor(p, 2);
    p += __shfl_xor(p, 4); p += __shfl_xor(p, 8);
    if (n == 0) {
      const float zv = xz[m * 768 + DINNER + d];
      yg[m * DINNER + d] = (p + Dv * uv) * silu_f(zv);
    }
  }
}

extern "C" void kernel_launch(void* const* d_in, const int* in_sizes, int n_in,
                              void* d_out, int out_size, void* d_ws, size_t ws_size,
                              hipStream_t stream) {
  const float* hs   = (const float*)d_in[0];
  const float* in_w = (const float*)d_in[1];
  const float* cw   = (const float*)d_in[2];
  const float* cb   = (const float*)d_in[3];
  const float* xw   = (const float*)d_in[4];
  const float* dtw  = (const float*)d_in[5];
  const float* dtb  = (const float*)d_in[6];
  const float* alog = (const float*)d_in[7];
  const float* dsk  = (const float*)d_in[8];
  const float* ow   = (const float*)d_in[9];
  float* out = (float*)d_out;

  char* ws = (char*)d_ws;
  float* xz   = (float*)(ws);                                       // [M][768] 100.7 MB
  float* u    = (float*)(ws + (size_t)MTOT * 768 * 4);              // [M][384]  50.3 MB (reused as y)
  float* xdbl = (float*)(ws + (size_t)MTOT * (768 + 384) * 4);      // [M][44]    5.8 MB
  float* dt   = (float*)(ws + (size_t)MTOT * (768 + 384 + XDBL) * 4); // [M][384] 50.3 MB

  // 1. in_proj: xz = hs @ in_proj_w^T
  gemm_rt<DMODEL><<<dim3(768 / 64, MTOT / 64), 256, 0, stream>>>(hs, in_w, xz, 768);
  // 2. depthwise conv + SiLU -> u
  conv_silu_k<<<(MTOT * DINNER) / 256, 256, 0, stream>>>(xz, cw, cb, u);
  // 3. x_proj: x_dbl = u @ x_proj_w^T
  xproj_k<<<MTOT / 64, 256, 0, stream>>>(u, xw, xdbl);
  // 4. dt_proj + softplus (double bias per reference)
  dtproj_k<<<(MTOT * DINNER) / 256, 256, 0, stream>>>(xdbl, dtw, dtb, dt);
  // 5. selective scan + D-skip + silu(z) gating -> y (in place over u)
  scan_k<<<dim3(DINNER / 16, BATCH), 256, 0, stream>>>(dt, u, xdbl, alog, dsk, xz, u);
  // 6. out_proj
  gemm_rt<DINNER><<<dim3(192 / 64, MTOT / 64), 256, 0, stream>>>(u, ow, out, 192);
}

// Round 2
// 932.472 us; speedup vs baseline: 3.8324x; 3.8324x over previous
//
#include <hip/hip_runtime.h>
#include <cmath>

#define BATCH 8
#define SEQLEN 4096
#define DMODEL 192
#define DINNER 384
#define DSTATE 16
#define DTRANK 12
#define XDBL 44            // DT_RANK + 2*D_STATE
#define MTOT (BATCH*SEQLEN)
#define CH 64              // scan chunk length
#define NC (SEQLEN/CH)     // 64 chunks

__device__ __forceinline__ float silu_f(float x) { return x / (1.f + __expf(-x)); }

// C[M][N] = A[M][K] @ W[N][K]^T   (both operands K-contiguous, torch-style weights)
// 64x64 tile, 256 threads, 4x4 micro-tile per thread. fp32 VALU.
template<int K>
__global__ __launch_bounds__(256) void gemm_rt(const float* __restrict__ A,
                                               const float* __restrict__ W,
                                               float* __restrict__ C, int N) {
  constexpr int BM = 64, BK = 16, PAD = 68;   // PAD=68 -> <=2-way LDS conflicts
  __shared__ float As[BK * PAD];
  __shared__ float Ws[BK * PAD];
  const int tid = threadIdx.x;
  const int m0 = blockIdx.y * BM, n0 = blockIdx.x * 64;
  const int lk = (tid & 3) * 4;   // k offset of this thread's float4
  const int lm = tid >> 2;        // row 0..63
  const int tx = tid & 15, ty = tid >> 4;
  float acc[4][4] = {};
  for (int k0 = 0; k0 < K; k0 += BK) {
    float4 av = *(const float4*)(A + (size_t)(m0 + lm) * K + (k0 + lk));
    float4 wv = *(const float4*)(W + (size_t)(n0 + lm) * K + (k0 + lk));
    __syncthreads();
    As[(lk + 0) * PAD + lm] = av.x; As[(lk + 1) * PAD + lm] = av.y;
    As[(lk + 2) * PAD + lm] = av.z; As[(lk + 3) * PAD + lm] = av.w;
    Ws[(lk + 0) * PAD + lm] = wv.x; Ws[(lk + 1) * PAD + lm] = wv.y;
    Ws[(lk + 2) * PAD + lm] = wv.z; Ws[(lk + 3) * PAD + lm] = wv.w;
    __syncthreads();
#pragma unroll
    for (int kk = 0; kk < BK; kk++) {
      float4 a = *(const float4*)&As[kk * PAD + ty * 4];
      float4 b = *(const float4*)&Ws[kk * PAD + tx * 4];
      float ar[4] = {a.x, a.y, a.z, a.w}, br[4] = {b.x, b.y, b.z, b.w};
#pragma unroll
      for (int i = 0; i < 4; i++)
#pragma unroll
        for (int j = 0; j < 4; j++)
          acc[i][j] = fmaf(ar[i], br[j], acc[i][j]);
    }
  }
#pragma unroll
  for (int i = 0; i < 4; i++) {
    float4 o = make_float4(acc[i][0], acc[i][1], acc[i][2], acc[i][3]);
    *(float4*)(C + (size_t)(m0 + ty * 4 + i) * N + (n0 + tx * 4)) = o;
  }
}

// depthwise conv (k=3, same-pad, cross-correlation like jax.lax.conv) + SiLU
__global__ __launch_bounds__(256) void conv_silu_k(const float* __restrict__ xz,
                                                   const float* __restrict__ cw,
                                                   const float* __restrict__ cb,
                                                   float* __restrict__ u) {
  const int idx = blockIdx.x * 256 + threadIdx.x;   // m*DINNER + d
  const int d = idx % DINNER;
  const int m = idx / DINNER;
  const int l = m % SEQLEN;
  const float w0 = cw[d * 3 + 0], w1 = cw[d * 3 + 1], w2 = cw[d * 3 + 2];
  float s = cb[d] + w1 * xz[(size_t)m * 768 + d];
  if (l > 0)          s += w0 * xz[(size_t)(m - 1) * 768 + d];
  if (l < SEQLEN - 1) s += w2 * xz[(size_t)(m + 1) * 768 + d];
  u[idx] = silu_f(s);
}

// x_dbl[M][44] = u[M][384] @ x_proj_w[44][384]^T   (skinny GEMM, LDS-stage rows)
__global__ __launch_bounds__(256) void xproj_k(const float* __restrict__ u,
                                               const float* __restrict__ xw,
                                               float* __restrict__ xdbl) {
  __shared__ float Us[64 * 388];    // stride 388 -> 2-way conflicts max
  const int tid = threadIdx.x;
  const size_t m0 = (size_t)blockIdx.x * 64;
  for (int i = tid; i < 64 * 96; i += 256) {        // 96 float4 per row
    const int r = i / 96, c = (i % 96) * 4;
    float4 v = *(const float4*)(u + (m0 + r) * DINNER + c);
    float* dst = &Us[r * 388 + c];
    dst[0] = v.x; dst[1] = v.y; dst[2] = v.z; dst[3] = v.w;
  }
  __syncthreads();
  const int r = tid >> 2, ng = tid & 3;
  const float* urow = &Us[r * 388];
  for (int n = ng; n < XDBL; n += 4) {
    const float* wr = xw + (size_t)n * DINNER;
    float s = 0.f;
#pragma unroll 4
    for (int k = 0; k < DINNER; k += 4) {
      float4 uu = *(const float4*)(urow + k);
      float4 ww = *(const float4*)(wr + k);
      s = fmaf(uu.x, ww.x, s); s = fmaf(uu.y, ww.y, s);
      s = fmaf(uu.z, ww.z, s); s = fmaf(uu.w, ww.w, s);
    }
    xdbl[(m0 + r) * XDBL + n] = s;
  }
}

// dt[M][384] = softplus(x_dbl[:, :12] @ dt_proj_w^T + 2*dt_proj_b)  (ref adds bias twice)
__global__ __launch_bounds__(256) void dtproj_k(const float* __restrict__ xdbl,
                                                const float* __restrict__ dtw,
                                                const float* __restrict__ dtb,
                                                float* __restrict__ dt) {
  const int idx = blockIdx.x * 256 + threadIdx.x;   // m*DINNER + d
  const int d = idx % DINNER;
  const size_t m = idx / DINNER;
  const float* xr = xdbl + m * XDBL;
  const float* wr = dtw + d * DTRANK;
  float s = 2.f * dtb[d];
#pragma unroll
  for (int r = 0; r < DTRANK; r++) s = fmaf(xr[r], wr[r], s);
  dt[idx] = (s > 20.f) ? s : log1pf(__expf(s));
}

// ---- chunked parallel scan (linear recurrence decomposition) ----
// h[l] = a[l]*h[l-1] + b[l], a = exp(dt*A) in (0,1].
// Pass 1: per chunk, P = prod(a), S = local scan end-state with h0=0.
__global__ __launch_bounds__(256) void scan_part1(const float* __restrict__ dt,
                                                  const float* __restrict__ u,
                                                  const float* __restrict__ xdbl,
                                                  const float* __restrict__ A_log,
                                                  float* __restrict__ Pbuf,
                                                  float* __restrict__ Sbuf) {
  const int tid = threadIdx.x;
  const int n = tid & 15, dd = tid >> 4;
  const int d = blockIdx.x * 16 + dd;
  const int c = blockIdx.y;
  const int b = blockIdx.z;
  const float Av = -expf(A_log[d * DSTATE + n]);
  float P = 1.f, S = 0.f;
  const size_t mbase = (size_t)b * SEQLEN + (size_t)c * CH;
  for (int l = 0; l < CH; l++) {
    const size_t m = mbase + l;
    const float dtv = dt[m * DINNER + d];
    const float uv  = u[m * DINNER + d];
    const float Bv  = xdbl[m * XDBL + DTRANK + n];
    const float a = __expf(dtv * Av);
    S = fmaf(a, S, dtv * uv * Bv);
    P *= a;
  }
  const size_t idx = ((size_t)(b * NC + c) * DINNER + d) * DSTATE + n;
  Pbuf[idx] = P;
  Sbuf[idx] = S;
}

// Pass 2: sequential combine across chunks per (b,d,n); overwrite Pbuf with h0 per chunk.
__global__ __launch_bounds__(256) void scan_part2(float* __restrict__ Pbuf,
                                                  const float* __restrict__ Sbuf) {
  const int i = blockIdx.x * 256 + threadIdx.x;    // b*(DINNER*DSTATE) + r
  const int b = i / (DINNER * DSTATE);
  const int r = i % (DINNER * DSTATE);
  float h = 0.f;
  for (int c = 0; c < NC; c++) {
    const size_t idx = (size_t)(b * NC + c) * (DINNER * DSTATE) + r;
    const float p = Pbuf[idx], s = Sbuf[idx];
    Pbuf[idx] = h;                 // h0 entering this chunk
    h = fmaf(p, h, s);
  }
}

// Pass 3: re-run recurrence per chunk from its h0; emit gated y (over u, in place).
__global__ __launch_bounds__(256) void scan_part3(const float* __restrict__ dt,
                                                  const float* __restrict__ u,
                                                  const float* __restrict__ xdbl,
                                                  const float* __restrict__ A_log,
                                                  const float* __restrict__ Dsk,
                                                  const float* __restrict__ xz,
                                                  const float* __restrict__ H0,
                                                  float* __restrict__ yg) {
  const int tid = threadIdx.x;
  const int n = tid & 15, dd = tid >> 4;
  const int d = blockIdx.x * 16 + dd;
  const int c = blockIdx.y;
  const int b = blockIdx.z;
  const float Av = -expf(A_log[d * DSTATE + n]);
  const float Dv = Dsk[d];
  float h = H0[((size_t)(b * NC + c) * DINNER + d) * DSTATE + n];
  const size_t mbase = (size_t)b * SEQLEN + (size_t)c * CH;
  for (int l = 0; l < CH; l++) {
    const size_t m = mbase + l;
    const float dtv = dt[m * DINNER + d];
    const float uv  = u[m * DINNER + d];
    const float Bv  = xdbl[m * XDBL + DTRANK + n];
    const float Cv  = xdbl[m * XDBL + DTRANK + DSTATE + n];
    h = fmaf(__expf(dtv * Av), h, dtv * uv * Bv);
    float p = h * Cv;
    p += __shfl_xor(p, 1); p += __shfl_xor(p, 2);
    p += __shfl_xor(p, 4); p += __shfl_xor(p, 8);
    if (n == 0) {
      const float zv = xz[m * 768 + DINNER + d];
      yg[m * DINNER + d] = (p + Dv * uv) * silu_f(zv);
    }
  }
}

extern "C" void kernel_launch(void* const* d_in, const int* in_sizes, int n_in,
                              void* d_out, int out_size, void* d_ws, size_t ws_size,
                              hipStream_t stream) {
  const float* hs   = (const float*)d_in[0];
  const float* in_w = (const float*)d_in[1];
  const float* cw   = (const float*)d_in[2];
  const float* cb   = (const float*)d_in[3];
  const float* xw   = (const float*)d_in[4];
  const float* dtw  = (const float*)d_in[5];
  const float* dtb  = (const float*)d_in[6];
  const float* alog = (const float*)d_in[7];
  const float* dsk  = (const float*)d_in[8];
  const float* ow   = (const float*)d_in[9];
  float* out = (float*)d_out;

  char* ws = (char*)d_ws;
  float* xz   = (float*)(ws);                                         // [M][768] 100.7 MB
  float* u    = (float*)(ws + (size_t)MTOT * 768 * 4);                // [M][384]  50.3 MB (reused as y)
  float* xdbl = (float*)(ws + (size_t)MTOT * (768 + 384) * 4);        // [M][44]    5.8 MB
  float* dt   = (float*)(ws + (size_t)MTOT * (768 + 384 + XDBL) * 4); // [M][384]  50.3 MB
  float* Pbuf = (float*)(ws + (size_t)MTOT * (768 + 384 + XDBL + 384) * 4);          // [B][NC][D][N] 12.6 MB (becomes h0)
  float* Sbuf = (float*)(ws + (size_t)MTOT * (768 + 384 + XDBL + 384) * 4
                            + (size_t)BATCH * NC * DINNER * DSTATE * 4);             // 12.6 MB

  // 1. in_proj: xz = hs @ in_proj_w^T
  gemm_rt<DMODEL><<<dim3(768 / 64, MTOT / 64), 256, 0, stream>>>(hs, in_w, xz, 768);
  // 2. depthwise conv + SiLU -> u
  conv_silu_k<<<(MTOT * DINNER) / 256, 256, 0, stream>>>(xz, cw, cb, u);
  // 3. x_proj: x_dbl = u @ x_proj_w^T
  xproj_k<<<MTOT / 64, 256, 0, stream>>>(u, xw, xdbl);
  // 4. dt_proj + softplus (double bias per reference)
  dtproj_k<<<(MTOT * DINNER) / 256, 256, 0, stream>>>(xdbl, dtw, dtb, dt);
  // 5. chunked selective scan
  scan_part1<<<dim3(DINNER / 16, NC, BATCH), 256, 0, stream>>>(dt, u, xdbl, alog, Pbuf, Sbuf);
  scan_part2<<<(BATCH * DINNER * DSTATE) / 256, 256, 0, stream>>>(Pbuf, Sbuf);
  scan_part3<<<dim3(DINNER / 16, NC, BATCH), 256, 0, stream>>>(dt, u, xdbl, alog, dsk, xz, Pbuf, u);
  // 6. out_proj
  gemm_rt<DINNER><<<dim3(192 / 64, MTOT / 64), 256, 0, stream>>>(u, ow, out, 192);
}

// Round 3
// 655.056 us; speedup vs baseline: 5.4554x; 1.4235x over previous
//
#include <hip/hip_runtime.h>
#include <cmath>

#define BATCH 8
#define SEQLEN 4096
#define DMODEL 192
#define DINNER 384
#define DSTATE 16
#define DTRANK 12
#define XDBL 44            // DT_RANK + 2*D_STATE
#define MTOT (BATCH*SEQLEN)
#define CH 64              // scan chunk length
#define NC (SEQLEN/CH)     // 64 chunks

__device__ __forceinline__ float silu_f(float x) { return x / (1.f + __expf(-x)); }

// C[M][N] = A[M][K] @ W[N][K]^T   (both operands K-contiguous, torch-style weights)
// 64x64 tile, 256 threads, 4x4 micro-tile per thread. fp32 VALU.
template<int K>
__global__ __launch_bounds__(256) void gemm_rt(const float* __restrict__ A,
                                               const float* __restrict__ W,
                                               float* __restrict__ C, int N) {
  constexpr int BM = 64, BK = 16, PAD = 68;   // PAD=68 -> <=2-way LDS conflicts
  __shared__ float As[BK * PAD];
  __shared__ float Ws[BK * PAD];
  const int tid = threadIdx.x;
  const int m0 = blockIdx.y * BM, n0 = blockIdx.x * 64;
  const int lk = (tid & 3) * 4;   // k offset of this thread's float4
  const int lm = tid >> 2;        // row 0..63
  const int tx = tid & 15, ty = tid >> 4;
  float acc[4][4] = {};
  for (int k0 = 0; k0 < K; k0 += BK) {
    float4 av = *(const float4*)(A + (size_t)(m0 + lm) * K + (k0 + lk));
    float4 wv = *(const float4*)(W + (size_t)(n0 + lm) * K + (k0 + lk));
    __syncthreads();
    As[(lk + 0) * PAD + lm] = av.x; As[(lk + 1) * PAD + lm] = av.y;
    As[(lk + 2) * PAD + lm] = av.z; As[(lk + 3) * PAD + lm] = av.w;
    Ws[(lk + 0) * PAD + lm] = wv.x; Ws[(lk + 1) * PAD + lm] = wv.y;
    Ws[(lk + 2) * PAD + lm] = wv.z; Ws[(lk + 3) * PAD + lm] = wv.w;
    __syncthreads();
#pragma unroll
    for (int kk = 0; kk < BK; kk++) {
      float4 a = *(const float4*)&As[kk * PAD + ty * 4];
      float4 b = *(const float4*)&Ws[kk * PAD + tx * 4];
      float ar[4] = {a.x, a.y, a.z, a.w}, br[4] = {b.x, b.y, b.z, b.w};
#pragma unroll
      for (int i = 0; i < 4; i++)
#pragma unroll
        for (int j = 0; j < 4; j++)
          acc[i][j] = fmaf(ar[i], br[j], acc[i][j]);
    }
  }
#pragma unroll
  for (int i = 0; i < 4; i++) {
    float4 o = make_float4(acc[i][0], acc[i][1], acc[i][2], acc[i][3]);
    *(float4*)(C + (size_t)(m0 + ty * 4 + i) * N + (n0 + tx * 4)) = o;
  }
}

// depthwise conv (k=3, same-pad, cross-correlation like jax.lax.conv) + SiLU
__global__ __launch_bounds__(256) void conv_silu_k(const float* __restrict__ xz,
                                                   const float* __restrict__ cw,
                                                   const float* __restrict__ cb,
                                                   float* __restrict__ u) {
  const int idx = blockIdx.x * 256 + threadIdx.x;   // m*DINNER + d
  const int d = idx % DINNER;
  const int m = idx / DINNER;
  const int l = m % SEQLEN;
  const float w0 = cw[d * 3 + 0], w1 = cw[d * 3 + 1], w2 = cw[d * 3 + 2];
  float s = cb[d] + w1 * xz[(size_t)m * 768 + d];
  if (l > 0)          s += w0 * xz[(size_t)(m - 1) * 768 + d];
  if (l < SEQLEN - 1) s += w2 * xz[(size_t)(m + 1) * 768 + d];
  u[idx] = silu_f(s);
}

// x_dbl[M][44] = u[M][384] @ x_proj_w[44][384]^T   (skinny GEMM, LDS-stage rows)
__global__ __launch_bounds__(256) void xproj_k(const float* __restrict__ u,
                                               const float* __restrict__ xw,
                                               float* __restrict__ xdbl) {
  __shared__ float Us[64 * 388];    // stride 388 -> 2-way conflicts max
  const int tid = threadIdx.x;
  const size_t m0 = (size_t)blockIdx.x * 64;
  for (int i = tid; i < 64 * 96; i += 256) {        // 96 float4 per row
    const int r = i / 96, c = (i % 96) * 4;
    float4 v = *(const float4*)(u + (m0 + r) * DINNER + c);
    float* dst = &Us[r * 388 + c];
    dst[0] = v.x; dst[1] = v.y; dst[2] = v.z; dst[3] = v.w;
  }
  __syncthreads();
  const int r = tid >> 2, ng = tid & 3;
  const float* urow = &Us[r * 388];
  for (int n = ng; n < XDBL; n += 4) {
    const float* wr = xw + (size_t)n * DINNER;
    float s = 0.f;
#pragma unroll 4
    for (int k = 0; k < DINNER; k += 4) {
      float4 uu = *(const float4*)(urow + k);
      float4 ww = *(const float4*)(wr + k);
      s = fmaf(uu.x, ww.x, s); s = fmaf(uu.y, ww.y, s);
      s = fmaf(uu.z, ww.z, s); s = fmaf(uu.w, ww.w, s);
    }
    xdbl[(m0 + r) * XDBL + n] = s;
  }
}

// dt[M][384] = softplus(x_dbl[:, :12] @ dt_proj_w^T + 2*dt_proj_b)  (ref adds bias twice)
__global__ __launch_bounds__(256) void dtproj_k(const float* __restrict__ xdbl,
                                                const float* __restrict__ dtw,
                                                const float* __restrict__ dtb,
                                                float* __restrict__ dt) {
  const int idx = blockIdx.x * 256 + threadIdx.x;   // m*DINNER + d
  const int d = idx % DINNER;
  const size_t m = idx / DINNER;
  const float* xr = xdbl + m * XDBL;
  const float* wr = dtw + d * DTRANK;
  float s = 2.f * dtb[d];
#pragma unroll
  for (int r = 0; r < DTRANK; r++) s = fmaf(xr[r], wr[r], s);
  dt[idx] = (s > 20.f) ? s : log1pf(__expf(s));
}

// ---- chunked parallel scan, thread-per-(b,d), 16 states in registers ----
// h[l] = a[l]*h[l-1] + b[l], a = exp(dt*A) in (0,1].
// Pass 1: per chunk, P = prod(a) = exp(A*sum(dt)), S = local end-state with h0=0.
__global__ __launch_bounds__(384) void scan_part1(const float* __restrict__ dt,
                                                  const float* __restrict__ u,
                                                  const float* __restrict__ xdbl,
                                                  const float* __restrict__ A_log,
                                                  float* __restrict__ Pbuf,
                                                  float* __restrict__ Sbuf) {
  __shared__ float Bs[CH][DSTATE];            // 4 KB, broadcast reads
  const int d = threadIdx.x;                  // 0..383
  const int c = blockIdx.x, b = blockIdx.y;
  const size_t mbase = (size_t)b * SEQLEN + (size_t)c * CH;
  // stage B chunk: 64 rows x 4 float4
  if (d < CH * 4) {
    const int r = d >> 2, q = d & 3;
    float4 v = *(const float4*)(xdbl + (mbase + r) * XDBL + DTRANK + q * 4);
    float* dst = &Bs[r][q * 4];
    dst[0] = v.x; dst[1] = v.y; dst[2] = v.z; dst[3] = v.w;
  }
  float Av[DSTATE];
#pragma unroll
  for (int q = 0; q < 4; q++) {
    float4 v = *(const float4*)(A_log + d * DSTATE + q * 4);
    Av[q * 4 + 0] = -__expf(v.x); Av[q * 4 + 1] = -__expf(v.y);
    Av[q * 4 + 2] = -__expf(v.z); Av[q * 4 + 3] = -__expf(v.w);
  }
  float h[DSTATE];
#pragma unroll
  for (int n = 0; n < DSTATE; n++) h[n] = 0.f;
  float dtsum = 0.f;
  __syncthreads();
  float dtv = dt[mbase * DINNER + d];
  float uv  = u[mbase * DINNER + d];
  for (int l = 0; l < CH; l++) {
    const int lp = (l + 1 < CH) ? (l + 1) : l;
    const float dtn = dt[(mbase + lp) * DINNER + d];
    const float un  = u[(mbase + lp) * DINNER + d];
    const float du = dtv * uv;
    dtsum += dtv;
#pragma unroll
    for (int n = 0; n < DSTATE; n++) {
      const float a = __expf(dtv * Av[n]);
      h[n] = fmaf(a, h[n], du * Bs[l][n]);
    }
    dtv = dtn; uv = un;
  }
  float* Pp = Pbuf + ((size_t)(b * NC + c) * DINNER + d) * DSTATE;
  float* Sp = Sbuf + ((size_t)(b * NC + c) * DINNER + d) * DSTATE;
#pragma unroll
  for (int q = 0; q < 4; q++) {
    float4 pv, sv;
    pv.x = __expf(dtsum * Av[q * 4 + 0]); pv.y = __expf(dtsum * Av[q * 4 + 1]);
    pv.z = __expf(dtsum * Av[q * 4 + 2]); pv.w = __expf(dtsum * Av[q * 4 + 3]);
    sv.x = h[q * 4 + 0]; sv.y = h[q * 4 + 1]; sv.z = h[q * 4 + 2]; sv.w = h[q * 4 + 3];
    *(float4*)(Pp + q * 4) = pv;
    *(float4*)(Sp + q * 4) = sv;
  }
}

// Pass 2: sequential combine across chunks per (b,d,n); overwrite Pbuf with h0 per chunk.
__global__ __launch_bounds__(256) void scan_part2(float* __restrict__ Pbuf,
                                                  const float* __restrict__ Sbuf) {
  const int i = blockIdx.x * 256 + threadIdx.x;    // b*(DINNER*DSTATE) + r
  const int b = i / (DINNER * DSTATE);
  const int r = i % (DINNER * DSTATE);
  float h = 0.f;
  for (int c = 0; c < NC; c++) {
    const size_t idx = (size_t)(b * NC + c) * (DINNER * DSTATE) + r;
    const float p = Pbuf[idx], s = Sbuf[idx];
    Pbuf[idx] = h;                 // h0 entering this chunk
    h = fmaf(p, h, s);
  }
}

// Pass 3: re-run recurrence per chunk from h0; y = (h.C + D*u)*silu(z), over u in place.
__global__ __launch_bounds__(384) void scan_part3(const float* __restrict__ dt,
                                                  const float* __restrict__ u,
                                                  const float* __restrict__ xdbl,
                                                  const float* __restrict__ A_log,
                                                  const float* __restrict__ Dsk,
                                                  const float* __restrict__ xz,
                                                  const float* __restrict__ H0,
                                                  float* __restrict__ yg) {
  __shared__ float BC[CH][2 * DSTATE];        // 8 KB: [l][0..15]=B, [l][16..31]=C
  const int d = threadIdx.x;
  const int c = blockIdx.x, b = blockIdx.y;
  const size_t mbase = (size_t)b * SEQLEN + (size_t)c * CH;
  for (int i = d; i < CH * 8; i += 384) {     // 64 rows x 8 float4 (B+C)
    const int r = i >> 3, q = i & 7;
    float4 v = *(const float4*)(xdbl + (mbase + r) * XDBL + DTRANK + q * 4);
    float* dst = &BC[r][q * 4];
    dst[0] = v.x; dst[1] = v.y; dst[2] = v.z; dst[3] = v.w;
  }
  float Av[DSTATE];
#pragma unroll
  for (int q = 0; q < 4; q++) {
    float4 v = *(const float4*)(A_log + d * DSTATE + q * 4);
    Av[q * 4 + 0] = -__expf(v.x); Av[q * 4 + 1] = -__expf(v.y);
    Av[q * 4 + 2] = -__expf(v.z); Av[q * 4 + 3] = -__expf(v.w);
  }
  const float Dv = Dsk[d];
  float h[DSTATE];
  {
    const float* Hp = H0 + ((size_t)(b * NC + c) * DINNER + d) * DSTATE;
#pragma unroll
    for (int q = 0; q < 4; q++) {
      float4 v = *(const float4*)(Hp + q * 4);
      h[q * 4 + 0] = v.x; h[q * 4 + 1] = v.y; h[q * 4 + 2] = v.z; h[q * 4 + 3] = v.w;
    }
  }
  __syncthreads();
  float dtv = dt[mbase * DINNER + d];
  float uv  = u[mbase * DINNER + d];
  float zv  = xz[mbase * 768 + DINNER + d];
  for (int l = 0; l < CH; l++) {
    const int lp = (l + 1 < CH) ? (l + 1) : l;
    const float dtn = dt[(mbase + lp) * DINNER + d];
    const float un  = u[(mbase + lp) * DINNER + d];
    const float zn  = xz[(mbase + lp) * 768 + DINNER + d];
    const float du = dtv * uv;
    float yacc = Dv * uv;
#pragma unroll
    for (int n = 0; n < DSTATE; n++) {
      const float a = __expf(dtv * Av[n]);
      h[n] = fmaf(a, h[n], du * BC[l][n]);
      yacc = fmaf(h[n], BC[l][DSTATE + n], yacc);
    }
    yg[(mbase + l) * DINNER + d] = yacc * silu_f(zv);
    dtv = dtn; uv = un; zv = zn;
  }
}

extern "C" void kernel_launch(void* const* d_in, const int* in_sizes, int n_in,
                              void* d_out, int out_size, void* d_ws, size_t ws_size,
                              hipStream_t stream) {
  const float* hs   = (const float*)d_in[0];
  const float* in_w = (const float*)d_in[1];
  const float* cw   = (const float*)d_in[2];
  const float* cb   = (const float*)d_in[3];
  const float* xw   = (const float*)d_in[4];
  const float* dtw  = (const float*)d_in[5];
  const float* dtb  = (const float*)d_in[6];
  const float* alog = (const float*)d_in[7];
  const float* dsk  = (const float*)d_in[8];
  const float* ow   = (const float*)d_in[9];
  float* out = (float*)d_out;

  char* ws = (char*)d_ws;
  float* xz   = (float*)(ws);                                         // [M][768] 100.7 MB
  float* u    = (float*)(ws + (size_t)MTOT * 768 * 4);                // [M][384]  50.3 MB (reused as y)
  float* xdbl = (float*)(ws + (size_t)MTOT * (768 + 384) * 4);        // [M][44]    5.8 MB
  float* dt   = (float*)(ws + (size_t)MTOT * (768 + 384 + XDBL) * 4); // [M][384]  50.3 MB
  float* Pbuf = (float*)(ws + (size_t)MTOT * (768 + 384 + XDBL + 384) * 4);          // [B][NC][D][N] 12.6 MB (becomes h0)
  float* Sbuf = (float*)(ws + (size_t)MTOT * (768 + 384 + XDBL + 384) * 4
                            + (size_t)BATCH * NC * DINNER * DSTATE * 4);             // 12.6 MB

  // 1. in_proj: xz = hs @ in_proj_w^T
  gemm_rt<DMODEL><<<dim3(768 / 64, MTOT / 64), 256, 0, stream>>>(hs, in_w, xz, 768);
  // 2. depthwise conv + SiLU -> u
  conv_silu_k<<<(MTOT * DINNER) / 256, 256, 0, stream>>>(xz, cw, cb, u);
  // 3. x_proj: x_dbl = u @ x_proj_w^T
  xproj_k<<<MTOT / 64, 256, 0, stream>>>(u, xw, xdbl);
  // 4. dt_proj + softplus (double bias per reference)
  dtproj_k<<<(MTOT * DINNER) / 256, 256, 0, stream>>>(xdbl, dtw, dtb, dt);
  // 5. chunked selective scan (thread per (b,d), 16 states in regs)
  scan_part1<<<dim3(NC, BATCH), 384, 0, stream>>>(dt, u, xdbl, alog, Pbuf, Sbuf);
  scan_part2<<<(BATCH * DINNER * DSTATE) / 256, 256, 0, stream>>>(Pbuf, Sbuf);
  scan_part3<<<dim3(NC, BATCH), 384, 0, stream>>>(dt, u, xdbl, alog, dsk, xz, Pbuf, u);
  // 6. out_proj
  gemm_rt<DINNER><<<dim3(192 / 64, MTOT / 64), 256, 0, stream>>>(u, ow, out, 192);
}

// Round 4
// 440.756 us; speedup vs baseline: 8.1078x; 1.4862x over previous
//
#include <hip/hip_runtime.h>
#include <cmath>

#define BATCH 8
#define SEQLEN 4096
#define DMODEL 192
#define DINNER 384
#define DSTATE 16
#define DTRANK 12
#define XSTR 64            // padded x_dbl row stride (44 real cols)
#define MTOT (BATCH*SEQLEN)
#define CH 64              // scan chunk length
#define NC (SEQLEN/CH)     // 64 chunks

__device__ __forceinline__ float silu_f(float x) { return x / (1.f + __expf(-x)); }

// C[M][N] = A[M][K] @ W[N][K]^T. BM=128, BN=64, BK=16, 256 threads, 8x4 micro.
template<int K>
__global__ __launch_bounds__(256) void gemm2(const float* __restrict__ A,
                                             const float* __restrict__ W,
                                             float* __restrict__ C, int N) {
  __shared__ float As[16 * 132];   // [k][m], pad 132
  __shared__ float Ws[16 * 68];    // [k][n], pad 68
  const int tid = threadIdx.x;
  const int m0 = blockIdx.y * 128, n0 = blockIdx.x * 64;
  const int lm = tid >> 1, lk = (tid & 1) * 8;      // A stage: row, k-offset
  const int wn = tid >> 2, wk = (tid & 3) * 4;      // W stage: row, k-offset
  const int ty = tid >> 4, tx = tid & 15;           // micro: 8 rows ty*8.., 4 cols tx*4..
  float acc[8][4] = {};
  const float* Ap = A + (size_t)(m0 + lm) * K + lk;
  const float* Wp = W + (size_t)(n0 + wn) * K + wk;
  for (int k0 = 0; k0 < K; k0 += 16) {
    float4 av0 = *(const float4*)(Ap + k0);
    float4 av1 = *(const float4*)(Ap + k0 + 4);
    float4 wv  = *(const float4*)(Wp + k0);
    __syncthreads();
    As[(lk + 0) * 132 + lm] = av0.x; As[(lk + 1) * 132 + lm] = av0.y;
    As[(lk + 2) * 132 + lm] = av0.z; As[(lk + 3) * 132 + lm] = av0.w;
    As[(lk + 4) * 132 + lm] = av1.x; As[(lk + 5) * 132 + lm] = av1.y;
    As[(lk + 6) * 132 + lm] = av1.z; As[(lk + 7) * 132 + lm] = av1.w;
    Ws[(wk + 0) * 68 + wn] = wv.x; Ws[(wk + 1) * 68 + wn] = wv.y;
    Ws[(wk + 2) * 68 + wn] = wv.z; Ws[(wk + 3) * 68 + wn] = wv.w;
    __syncthreads();
#pragma unroll
    for (int kk = 0; kk < 16; kk++) {
      float4 a0 = *(const float4*)&As[kk * 132 + ty * 8];
      float4 a1 = *(const float4*)&As[kk * 132 + ty * 8 + 4];
      float4 b  = *(const float4*)&Ws[kk * 68 + tx * 4];
      float ar[8] = {a0.x, a0.y, a0.z, a0.w, a1.x, a1.y, a1.z, a1.w};
      float br[4] = {b.x, b.y, b.z, b.w};
#pragma unroll
      for (int i = 0; i < 8; i++)
#pragma unroll
        for (int j = 0; j < 4; j++)
          acc[i][j] = fmaf(ar[i], br[j], acc[i][j]);
    }
  }
#pragma unroll
  for (int i = 0; i < 8; i++) {
    float4 o = make_float4(acc[i][0], acc[i][1], acc[i][2], acc[i][3]);
    *(float4*)(C + (size_t)(m0 + ty * 8 + i) * N + (n0 + tx * 4)) = o;
  }
}

// zero-pad x_proj_w [44][384] -> [64][384]
__global__ __launch_bounds__(256) void wpad_k(const float* __restrict__ xw,
                                              float* __restrict__ wp) {
  const int idx = blockIdx.x * 256 + threadIdx.x;   // < 64*384
  const int r = idx / DINNER, c = idx % DINNER;
  wp[idx] = (r < 44) ? xw[r * DINNER + c] : 0.f;
}

// depthwise conv (k=3, same-pad) + SiLU
__global__ __launch_bounds__(256) void conv_silu_k(const float* __restrict__ xz,
                                                   const float* __restrict__ cw,
                                                   const float* __restrict__ cb,
                                                   float* __restrict__ u) {
  const int idx = blockIdx.x * 256 + threadIdx.x;   // m*DINNER + d
  const int d = idx % DINNER;
  const int m = idx / DINNER;
  const int l = m % SEQLEN;
  const float w0 = cw[d * 3 + 0], w1 = cw[d * 3 + 1], w2 = cw[d * 3 + 2];
  float s = cb[d] + w1 * xz[(size_t)m * 768 + d];
  if (l > 0)          s += w0 * xz[(size_t)(m - 1) * 768 + d];
  if (l < SEQLEN - 1) s += w2 * xz[(size_t)(m + 1) * 768 + d];
  u[idx] = silu_f(s);
}

// dt[M][384] = softplus(x_dbl[:, :12] @ dt_proj_w^T + 2*dt_proj_b)  (ref adds bias twice)
__global__ __launch_bounds__(256) void dtproj_k(const float* __restrict__ xdbl,
                                                const float* __restrict__ dtw,
                                                const float* __restrict__ dtb,
                                                float* __restrict__ dt) {
  const int idx = blockIdx.x * 256 + threadIdx.x;   // m*DINNER + d
  const int d = idx % DINNER;
  const size_t m = idx / DINNER;
  const float* xr = xdbl + m * XSTR;
  const float* wr = dtw + d * DTRANK;
  float s = 2.f * dtb[d];
#pragma unroll
  for (int r = 0; r < DTRANK; r++) s = fmaf(xr[r], wr[r], s);
  dt[idx] = (s > 20.f) ? s : log1pf(__expf(s));
}

// ---- chunked parallel scan, thread-per-(b,d), 16 states in registers ----
// Pass 1: per chunk, P = prod(a) = exp(A*sum(dt)), S = local end-state with h0=0.
__global__ __launch_bounds__(384) void scan_part1(const float* __restrict__ dt,
                                                  const float* __restrict__ u,
                                                  const float* __restrict__ xdbl,
                                                  const float* __restrict__ A_log,
                                                  float* __restrict__ Pbuf,
                                                  float* __restrict__ Sbuf) {
  __shared__ float Bs[CH][DSTATE];            // 4 KB, broadcast reads
  const int d = threadIdx.x;                  // 0..383
  const int c = blockIdx.x, b = blockIdx.y;
  const size_t mbase = (size_t)b * SEQLEN + (size_t)c * CH;
  if (d < CH * 4) {
    const int r = d >> 2, q = d & 3;
    float4 v = *(const float4*)(xdbl + (mbase + r) * XSTR + DTRANK + q * 4);
    float* dst = &Bs[r][q * 4];
    dst[0] = v.x; dst[1] = v.y; dst[2] = v.z; dst[3] = v.w;
  }
  float Av[DSTATE];
#pragma unroll
  for (int q = 0; q < 4; q++) {
    float4 v = *(const float4*)(A_log + d * DSTATE + q * 4);
    Av[q * 4 + 0] = -__expf(v.x); Av[q * 4 + 1] = -__expf(v.y);
    Av[q * 4 + 2] = -__expf(v.z); Av[q * 4 + 3] = -__expf(v.w);
  }
  float h[DSTATE];
#pragma unroll
  for (int n = 0; n < DSTATE; n++) h[n] = 0.f;
  float dtsum = 0.f;
  __syncthreads();
  float dtv = dt[mbase * DINNER + d];
  float uv  = u[mbase * DINNER + d];
  for (int l = 0; l < CH; l++) {
    const int lp = (l + 1 < CH) ? (l + 1) : l;
    const float dtn = dt[(mbase + lp) * DINNER + d];
    const float un  = u[(mbase + lp) * DINNER + d];
    const float du = dtv * uv;
    dtsum += dtv;
#pragma unroll
    for (int n = 0; n < DSTATE; n++) {
      const float a = __expf(dtv * Av[n]);
      h[n] = fmaf(a, h[n], du * Bs[l][n]);
    }
    dtv = dtn; uv = un;
  }
  float* Pp = Pbuf + ((size_t)(b * NC + c) * DINNER + d) * DSTATE;
  float* Sp = Sbuf + ((size_t)(b * NC + c) * DINNER + d) * DSTATE;
#pragma unroll
  for (int q = 0; q < 4; q++) {
    float4 pv, sv;
    pv.x = __expf(dtsum * Av[q * 4 + 0]); pv.y = __expf(dtsum * Av[q * 4 + 1]);
    pv.z = __expf(dtsum * Av[q * 4 + 2]); pv.w = __expf(dtsum * Av[q * 4 + 3]);
    sv.x = h[q * 4 + 0]; sv.y = h[q * 4 + 1]; sv.z = h[q * 4 + 2]; sv.w = h[q * 4 + 3];
    *(float4*)(Pp + q * 4) = pv;
    *(float4*)(Sp + q * 4) = sv;
  }
}

// Pass 2: sequential combine across chunks per (b,d,n); overwrite Pbuf with h0 per chunk.
__global__ __launch_bounds__(256) void scan_part2(float* __restrict__ Pbuf,
                                                  const float* __restrict__ Sbuf) {
  const int i = blockIdx.x * 256 + threadIdx.x;    // b*(DINNER*DSTATE) + r
  const int b = i / (DINNER * DSTATE);
  const int r = i % (DINNER * DSTATE);
  float h = 0.f;
  for (int c = 0; c < NC; c++) {
    const size_t idx = (size_t)(b * NC + c) * (DINNER * DSTATE) + r;
    const float p = Pbuf[idx], s = Sbuf[idx];
    Pbuf[idx] = h;                 // h0 entering this chunk
    h = fmaf(p, h, s);
  }
}

// Pass 3: re-run recurrence per chunk from h0; y = (h.C + D*u)*silu(z), over u in place.
__global__ __launch_bounds__(384) void scan_part3(const float* __restrict__ dt,
                                                  const float* __restrict__ u,
                                                  const float* __restrict__ xdbl,
                                                  const float* __restrict__ A_log,
                                                  const float* __restrict__ Dsk,
                                                  const float* __restrict__ xz,
                                                  const float* __restrict__ H0,
                                                  float* __restrict__ yg) {
  __shared__ float BC[CH][2 * DSTATE];        // 8 KB: [l][0..15]=B, [l][16..31]=C
  const int d = threadIdx.x;
  const int c = blockIdx.x, b = blockIdx.y;
  const size_t mbase = (size_t)b * SEQLEN + (size_t)c * CH;
  for (int i = d; i < CH * 8; i += 384) {     // 64 rows x 8 float4 (B+C)
    const int r = i >> 3, q = i & 7;
    float4 v = *(const float4*)(xdbl + (mbase + r) * XSTR + DTRANK + q * 4);
    float* dst = &BC[r][q * 4];
    dst[0] = v.x; dst[1] = v.y; dst[2] = v.z; dst[3] = v.w;
  }
  float Av[DSTATE];
#pragma unroll
  for (int q = 0; q < 4; q++) {
    float4 v = *(const float4*)(A_log + d * DSTATE + q * 4);
    Av[q * 4 + 0] = -__expf(v.x); Av[q * 4 + 1] = -__expf(v.y);
    Av[q * 4 + 2] = -__expf(v.z); Av[q * 4 + 3] = -__expf(v.w);
  }
  const float Dv = Dsk[d];
  float h[DSTATE];
  {
    const float* Hp = H0 + ((size_t)(b * NC + c) * DINNER + d) * DSTATE;
#pragma unroll
    for (int q = 0; q < 4; q++) {
      float4 v = *(const float4*)(Hp + q * 4);
      h[q * 4 + 0] = v.x; h[q * 4 + 1] = v.y; h[q * 4 + 2] = v.z; h[q * 4 + 3] = v.w;
    }
  }
  __syncthreads();
  float dtv = dt[mbase * DINNER + d];
  float uv  = u[mbase * DINNER + d];
  float zv  = xz[mbase * 768 + DINNER + d];
  for (int l = 0; l < CH; l++) {
    const int lp = (l + 1 < CH) ? (l + 1) : l;
    const float dtn = dt[(mbase + lp) * DINNER + d];
    const float un  = u[(mbase + lp) * DINNER + d];
    const float zn  = xz[(mbase + lp) * 768 + DINNER + d];
    const float du = dtv * uv;
    float yacc = Dv * uv;
#pragma unroll
    for (int n = 0; n < DSTATE; n++) {
      const float a = __expf(dtv * Av[n]);
      h[n] = fmaf(a, h[n], du * BC[l][n]);
      yacc = fmaf(h[n], BC[l][DSTATE + n], yacc);
    }
    yg[(mbase + l) * DINNER + d] = yacc * silu_f(zv);
    dtv = dtn; uv = un; zv = zn;
  }
}

extern "C" void kernel_launch(void* const* d_in, const int* in_sizes, int n_in,
                              void* d_out, int out_size, void* d_ws, size_t ws_size,
                              hipStream_t stream) {
  const float* hs   = (const float*)d_in[0];
  const float* in_w = (const float*)d_in[1];
  const float* cw   = (const float*)d_in[2];
  const float* cb   = (const float*)d_in[3];
  const float* xw   = (const float*)d_in[4];
  const float* dtw  = (const float*)d_in[5];
  const float* dtb  = (const float*)d_in[6];
  const float* alog = (const float*)d_in[7];
  const float* dsk  = (const float*)d_in[8];
  const float* ow   = (const float*)d_in[9];
  float* out = (float*)d_out;

  char* ws = (char*)d_ws;
  float* xz   = (float*)(ws);                                         // [M][768] 100.7 MB
  float* u    = (float*)(ws + (size_t)MTOT * 768 * 4);                // [M][384]  50.3 MB (reused as y)
  float* xdbl = (float*)(ws + (size_t)MTOT * (768 + 384) * 4);        // [M][64]    8.4 MB
  float* dt   = (float*)(ws + (size_t)MTOT * (768 + 384 + XSTR) * 4); // [M][384]  50.3 MB
  float* Pbuf = (float*)(ws + (size_t)MTOT * (768 + 384 + XSTR + 384) * 4);          // 12.6 MB (h0)
  float* Sbuf = (float*)(ws + (size_t)MTOT * (768 + 384 + XSTR + 384) * 4
                            + (size_t)BATCH * NC * DINNER * DSTATE * 4);             // 12.6 MB
  float* wpad = Pbuf;   // [64][384] 98 KB; used only before scan_part1 overwrites Pbuf

  // 1. in_proj: xz = hs @ in_proj_w^T
  gemm2<DMODEL><<<dim3(768 / 64, MTOT / 128), 256, 0, stream>>>(hs, in_w, xz, 768);
  // 2. depthwise conv + SiLU -> u
  conv_silu_k<<<(MTOT * DINNER) / 256, 256, 0, stream>>>(xz, cw, cb, u);
  // 3. x_proj as padded GEMM: x_dbl[M][64] = u @ wpad^T
  wpad_k<<<(XSTR * DINNER) / 256, 256, 0, stream>>>(xw, wpad);
  gemm2<DINNER><<<dim3(1, MTOT / 128), 256, 0, stream>>>(u, wpad, xdbl, XSTR);
  // 4. dt_proj + softplus (double bias per reference)
  dtproj_k<<<(MTOT * DINNER) / 256, 256, 0, stream>>>(xdbl, dtw, dtb, dt);
  // 5. chunked selective scan (thread per (b,d), 16 states in regs)
  scan_part1<<<dim3(NC, BATCH), 384, 0, stream>>>(dt, u, xdbl, alog, Pbuf, Sbuf);
  scan_part2<<<(BATCH * DINNER * DSTATE) / 256, 256, 0, stream>>>(Pbuf, Sbuf);
  scan_part3<<<dim3(NC, BATCH), 384, 0, stream>>>(dt, u, xdbl, alog, dsk, xz, Pbuf, u);
  // 6. out_proj
  gemm2<DINNER><<<dim3(192 / 64, MTOT / 128), 256, 0, stream>>>(u, ow, out, 192);
}

// Round 5
// 311.506 us; speedup vs baseline: 11.4719x; 1.4149x over previous
//
#include <hip/hip_runtime.h>
#include <cmath>

#define BATCH 8
#define SEQLEN 4096
#define DMODEL 192
#define DINNER 384
#define DSTATE 16
#define DTRANK 12
#define XSTR 64            // padded x_dbl row stride (44 real cols)
#define MTOT (BATCH*SEQLEN)
#define CH 64              // scan chunk length
#define NC (SEQLEN/CH)     // 64 chunks

typedef __bf16 bf16x8 __attribute__((ext_vector_type(8)));
typedef float f32x4 __attribute__((ext_vector_type(4)));
typedef unsigned short us8 __attribute__((ext_vector_type(8)));

__device__ __forceinline__ float silu_f(float x) { return x / (1.f + __expf(-x)); }
__device__ __forceinline__ unsigned short f2bf(float f) {
  unsigned u = __float_as_uint(f);
  return (unsigned short)((u + 0x7FFF + ((u >> 16) & 1)) >> 16);   // RNE
}
__device__ __forceinline__ float bf2f(unsigned short b) {
  return __uint_as_float(((unsigned)b) << 16);
}

// fp32 -> bf16 cast, 4 elems/thread
__global__ __launch_bounds__(256) void castf2b(const float* __restrict__ src,
                                               unsigned short* __restrict__ dst, int n4) {
  const int i = blockIdx.x * 256 + threadIdx.x;
  if (i < n4) {
    float4 v = ((const float4*)src)[i];
    ushort4 o;
    o.x = f2bf(v.x); o.y = f2bf(v.y); o.z = f2bf(v.z); o.w = f2bf(v.w);
    ((ushort4*)dst)[i] = o;
  }
}

// bf16 MFMA GEMM: C[M][N] = A[M][K] @ W[N][K]^T, fp32 accum.
// BM=128, BN=64, BK=32; 4 waves (2m x 2n), each 64x32 = 4x2 frags of 16x16x32.
// SPLIT (in_proj): cols 0..383 -> Cx fp32 [M][384]; cols 384..767 -> Zb bf16 [M][384].
template<int K, bool SPLIT>
__global__ __launch_bounds__(256) void gemm_bf16(const unsigned short* __restrict__ A,
                                                 const unsigned short* __restrict__ W,
                                                 float* __restrict__ Cx,
                                                 unsigned short* __restrict__ Zb,
                                                 int N) {
  __shared__ unsigned short Als[128 * 40];   // 80B rows: uniform bank spread
  __shared__ unsigned short Bls[64 * 40];
  const int tid = threadIdx.x;
  const int m0 = blockIdx.y * 128, n0 = blockIdx.x * 64;
  const int l = tid & 63;
  const int wm = ((tid >> 6) >> 1) * 64, wn = ((tid >> 6) & 1) * 32;
  const int lr = l & 15, lk8 = (l >> 4) * 8;
  const int ar = tid >> 1, ag = (tid & 1) * 16;    // A stage: row, elem offset
  const int br = tid >> 2, bg = (tid & 3) * 8;     // B stage
  const unsigned short* Ap = A + (size_t)(m0 + ar) * K + ag;
  const unsigned short* Wp = W + (size_t)(n0 + br) * K + bg;
  f32x4 acc[4][2];
#pragma unroll
  for (int i = 0; i < 4; i++)
#pragma unroll
    for (int j = 0; j < 2; j++) acc[i][j] = (f32x4){0.f, 0.f, 0.f, 0.f};
  for (int k0 = 0; k0 < K; k0 += 32) {
    us8 a0 = *(const us8*)(Ap + k0);
    us8 a1 = *(const us8*)(Ap + k0 + 8);
    us8 bv = *(const us8*)(Wp + k0);
    __syncthreads();
    *(us8*)(&Als[ar * 40 + ag]) = a0;
    *(us8*)(&Als[ar * 40 + ag + 8]) = a1;
    *(us8*)(&Bls[br * 40 + bg]) = bv;
    __syncthreads();
    bf16x8 b0 = *(const bf16x8*)(&Bls[(wn + lr) * 40 + lk8]);
    bf16x8 b1 = *(const bf16x8*)(&Bls[(wn + 16 + lr) * 40 + lk8]);
#pragma unroll
    for (int fm = 0; fm < 4; fm++) {
      bf16x8 af = *(const bf16x8*)(&Als[(wm + fm * 16 + lr) * 40 + lk8]);
      acc[fm][0] = __builtin_amdgcn_mfma_f32_16x16x32_bf16(af, b0, acc[fm][0], 0, 0, 0);
      acc[fm][1] = __builtin_amdgcn_mfma_f32_16x16x32_bf16(af, b1, acc[fm][1], 0, 0, 0);
    }
  }
  const int r0 = (l >> 4) * 4;   // C/D: col=lane&15, row=(lane>>4)*4+reg (m89-verified)
#pragma unroll
  for (int fm = 0; fm < 4; fm++) {
    const size_t rowb = (size_t)(m0 + wm + fm * 16 + r0);
#pragma unroll
    for (int fn = 0; fn < 2; fn++) {
      const int col = n0 + wn + fn * 16 + lr;
      if constexpr (SPLIT) {
        if (col < DINNER) {
#pragma unroll
          for (int r = 0; r < 4; r++) Cx[(rowb + r) * DINNER + col] = acc[fm][fn][r];
        } else {
#pragma unroll
          for (int r = 0; r < 4; r++) Zb[(rowb + r) * DINNER + (col - DINNER)] = f2bf(acc[fm][fn][r]);
        }
      } else {
#pragma unroll
        for (int r = 0; r < 4; r++) Cx[(rowb + r) * N + col] = acc[fm][fn][r];
      }
    }
  }
}

// fp32 GEMM (kept for x_proj only — its outputs feed the scan, keep full precision)
template<int K>
__global__ __launch_bounds__(256) void gemm2(const float* __restrict__ A,
                                             const float* __restrict__ W,
                                             float* __restrict__ C, int N) {
  __shared__ float As[16 * 132];
  __shared__ float Ws[16 * 68];
  const int tid = threadIdx.x;
  const int m0 = blockIdx.y * 128, n0 = blockIdx.x * 64;
  const int lm = tid >> 1, lk = (tid & 1) * 8;
  const int wn = tid >> 2, wk = (tid & 3) * 4;
  const int ty = tid >> 4, tx = tid & 15;
  float acc[8][4] = {};
  const float* Ap = A + (size_t)(m0 + lm) * K + lk;
  const float* Wp = W + (size_t)(n0 + wn) * K + wk;
  for (int k0 = 0; k0 < K; k0 += 16) {
    float4 av0 = *(const float4*)(Ap + k0);
    float4 av1 = *(const float4*)(Ap + k0 + 4);
    float4 wv  = *(const float4*)(Wp + k0);
    __syncthreads();
    As[(lk + 0) * 132 + lm] = av0.x; As[(lk + 1) * 132 + lm] = av0.y;
    As[(lk + 2) * 132 + lm] = av0.z; As[(lk + 3) * 132 + lm] = av0.w;
    As[(lk + 4) * 132 + lm] = av1.x; As[(lk + 5) * 132 + lm] = av1.y;
    As[(lk + 6) * 132 + lm] = av1.z; As[(lk + 7) * 132 + lm] = av1.w;
    Ws[(wk + 0) * 68 + wn] = wv.x; Ws[(wk + 1) * 68 + wn] = wv.y;
    Ws[(wk + 2) * 68 + wn] = wv.z; Ws[(wk + 3) * 68 + wn] = wv.w;
    __syncthreads();
#pragma unroll
    for (int kk = 0; kk < 16; kk++) {
      float4 a0 = *(const float4*)&As[kk * 132 + ty * 8];
      float4 a1 = *(const float4*)&As[kk * 132 + ty * 8 + 4];
      float4 b  = *(const float4*)&Ws[kk * 68 + tx * 4];
      float ar[8] = {a0.x, a0.y, a0.z, a0.w, a1.x, a1.y, a1.z, a1.w};
      float br[4] = {b.x, b.y, b.z, b.w};
#pragma unroll
      for (int i = 0; i < 8; i++)
#pragma unroll
        for (int j = 0; j < 4; j++)
          acc[i][j] = fmaf(ar[i], br[j], acc[i][j]);
    }
  }
#pragma unroll
  for (int i = 0; i < 8; i++) {
    float4 o = make_float4(acc[i][0], acc[i][1], acc[i][2], acc[i][3]);
    *(float4*)(C + (size_t)(m0 + ty * 8 + i) * N + (n0 + tx * 4)) = o;
  }
}

// zero-pad x_proj_w [44][384] -> [64][384]
__global__ __launch_bounds__(256) void wpad_k(const float* __restrict__ xw,
                                              float* __restrict__ wp) {
  const int idx = blockIdx.x * 256 + threadIdx.x;
  const int r = idx / DINNER, c = idx % DINNER;
  wp[idx] = (r < 44) ? xw[r * DINNER + c] : 0.f;
}

// depthwise conv (k=3, same-pad) + SiLU; x is [M][384] now
__global__ __launch_bounds__(256) void conv_silu_k(const float* __restrict__ x,
                                                   const float* __restrict__ cw,
                                                   const float* __restrict__ cb,
                                                   float* __restrict__ u) {
  const int idx = blockIdx.x * 256 + threadIdx.x;   // m*DINNER + d
  const int d = idx % DINNER;
  const int m = idx / DINNER;
  const int l = m % SEQLEN;
  const float w0 = cw[d * 3 + 0], w1 = cw[d * 3 + 1], w2 = cw[d * 3 + 2];
  float s = cb[d] + w1 * x[(size_t)m * DINNER + d];
  if (l > 0)          s += w0 * x[(size_t)(m - 1) * DINNER + d];
  if (l < SEQLEN - 1) s += w2 * x[(size_t)(m + 1) * DINNER + d];
  u[idx] = silu_f(s);
}

// dt[M][384] = softplus(x_dbl[:, :12] @ dt_proj_w^T + 2*dt_proj_b)  (ref adds bias twice)
__global__ __launch_bounds__(256) void dtproj_k(const float* __restrict__ xdbl,
                                                const float* __restrict__ dtw,
                                                const float* __restrict__ dtb,
                                                float* __restrict__ dt) {
  const int idx = blockIdx.x * 256 + threadIdx.x;
  const int d = idx % DINNER;
  const size_t m = idx / DINNER;
  const float* xr = xdbl + m * XSTR;
  const float* wr = dtw + d * DTRANK;
  float s = 2.f * dtb[d];
#pragma unroll
  for (int r = 0; r < DTRANK; r++) s = fmaf(xr[r], wr[r], s);
  dt[idx] = (s > 20.f) ? s : log1pf(__expf(s));
}

// ---- chunked parallel scan, thread-per-(b,d), 16 states in registers ----
__global__ __launch_bounds__(384) void scan_part1(const float* __restrict__ dt,
                                                  const float* __restrict__ u,
                                                  const float* __restrict__ xdbl,
                                                  const float* __restrict__ A_log,
                                                  float* __restrict__ Pbuf,
                                                  float* __restrict__ Sbuf) {
  __shared__ float Bs[CH][DSTATE];
  const int d = threadIdx.x;
  const int c = blockIdx.x, b = blockIdx.y;
  const size_t mbase = (size_t)b * SEQLEN + (size_t)c * CH;
  if (d < CH * 4) {
    const int r = d >> 2, q = d & 3;
    float4 v = *(const float4*)(xdbl + (mbase + r) * XSTR + DTRANK + q * 4);
    float* dst = &Bs[r][q * 4];
    dst[0] = v.x; dst[1] = v.y; dst[2] = v.z; dst[3] = v.w;
  }
  float Av[DSTATE];
#pragma unroll
  for (int q = 0; q < 4; q++) {
    float4 v = *(const float4*)(A_log + d * DSTATE + q * 4);
    Av[q * 4 + 0] = -__expf(v.x); Av[q * 4 + 1] = -__expf(v.y);
    Av[q * 4 + 2] = -__expf(v.z); Av[q * 4 + 3] = -__expf(v.w);
  }
  float h[DSTATE];
#pragma unroll
  for (int n = 0; n < DSTATE; n++) h[n] = 0.f;
  float dtsum = 0.f;
  __syncthreads();
  float dtv = dt[mbase * DINNER + d];
  float uv  = u[mbase * DINNER + d];
  for (int l = 0; l < CH; l++) {
    const int lp = (l + 1 < CH) ? (l + 1) : l;
    const float dtn = dt[(mbase + lp) * DINNER + d];
    const float un  = u[(mbase + lp) * DINNER + d];
    const float du = dtv * uv;
    dtsum += dtv;
#pragma unroll
    for (int n = 0; n < DSTATE; n++) {
      const float a = __expf(dtv * Av[n]);
      h[n] = fmaf(a, h[n], du * Bs[l][n]);
    }
    dtv = dtn; uv = un;
  }
  float* Pp = Pbuf + ((size_t)(b * NC + c) * DINNER + d) * DSTATE;
  float* Sp = Sbuf + ((size_t)(b * NC + c) * DINNER + d) * DSTATE;
#pragma unroll
  for (int q = 0; q < 4; q++) {
    float4 pv, sv;
    pv.x = __expf(dtsum * Av[q * 4 + 0]); pv.y = __expf(dtsum * Av[q * 4 + 1]);
    pv.z = __expf(dtsum * Av[q * 4 + 2]); pv.w = __expf(dtsum * Av[q * 4 + 3]);
    sv.x = h[q * 4 + 0]; sv.y = h[q * 4 + 1]; sv.z = h[q * 4 + 2]; sv.w = h[q * 4 + 3];
    *(float4*)(Pp + q * 4) = pv;
    *(float4*)(Sp + q * 4) = sv;
  }
}

__global__ __launch_bounds__(256) void scan_part2(float* __restrict__ Pbuf,
                                                  const float* __restrict__ Sbuf) {
  const int i = blockIdx.x * 256 + threadIdx.x;
  const int b = i / (DINNER * DSTATE);
  const int r = i % (DINNER * DSTATE);
  float h = 0.f;
  for (int c = 0; c < NC; c++) {
    const size_t idx = (size_t)(b * NC + c) * (DINNER * DSTATE) + r;
    const float p = Pbuf[idx], s = Sbuf[idx];
    Pbuf[idx] = h;
    h = fmaf(p, h, s);
  }
}

// Pass 3: re-run from h0; y = (h.C + D*u)*silu(z) emitted as bf16 for out_proj.
__global__ __launch_bounds__(384) void scan_part3(const float* __restrict__ dt,
                                                  const float* __restrict__ u,
                                                  const float* __restrict__ xdbl,
                                                  const float* __restrict__ A_log,
                                                  const float* __restrict__ Dsk,
                                                  const unsigned short* __restrict__ zb,
                                                  const float* __restrict__ H0,
                                                  unsigned short* __restrict__ yb) {
  __shared__ float BC[CH][2 * DSTATE];
  const int d = threadIdx.x;
  const int c = blockIdx.x, b = blockIdx.y;
  const size_t mbase = (size_t)b * SEQLEN + (size_t)c * CH;
  for (int i = d; i < CH * 8; i += 384) {
    const int r = i >> 3, q = i & 7;
    float4 v = *(const float4*)(xdbl + (mbase + r) * XSTR + DTRANK + q * 4);
    float* dst = &BC[r][q * 4];
    dst[0] = v.x; dst[1] = v.y; dst[2] = v.z; dst[3] = v.w;
  }
  float Av[DSTATE];
#pragma unroll
  for (int q = 0; q < 4; q++) {
    float4 v = *(const float4*)(A_log + d * DSTATE + q * 4);
    Av[q * 4 + 0] = -__expf(v.x); Av[q * 4 + 1] = -__expf(v.y);
    Av[q * 4 + 2] = -__expf(v.z); Av[q * 4 + 3] = -__expf(v.w);
  }
  const float Dv = Dsk[d];
  float h[DSTATE];
  {
    const float* Hp = H0 + ((size_t)(b * NC + c) * DINNER + d) * DSTATE;
#pragma unroll
    for (int q = 0; q < 4; q++) {
      float4 v = *(const float4*)(Hp + q * 4);
      h[q * 4 + 0] = v.x; h[q * 4 + 1] = v.y; h[q * 4 + 2] = v.z; h[q * 4 + 3] = v.w;
    }
  }
  __syncthreads();
  float dtv = dt[mbase * DINNER + d];
  float uv  = u[mbase * DINNER + d];
  float zv  = bf2f(zb[mbase * DINNER + d]);
  for (int l = 0; l < CH; l++) {
    const int lp = (l + 1 < CH) ? (l + 1) : l;
    const float dtn = dt[(mbase + lp) * DINNER + d];
    const float un  = u[(mbase + lp) * DINNER + d];
    const float zn  = bf2f(zb[(mbase + lp) * DINNER + d]);
    const float du = dtv * uv;
    float yacc = Dv * uv;
#pragma unroll
    for (int n = 0; n < DSTATE; n++) {
      const float a = __expf(dtv * Av[n]);
      h[n] = fmaf(a, h[n], du * BC[l][n]);
      yacc = fmaf(h[n], BC[l][DSTATE + n], yacc);
    }
    yb[(mbase + l) * DINNER + d] = f2bf(yacc * silu_f(zv));
    dtv = dtn; uv = un; zv = zn;
  }
}

extern "C" void kernel_launch(void* const* d_in, const int* in_sizes, int n_in,
                              void* d_out, int out_size, void* d_ws, size_t ws_size,
                              hipStream_t stream) {
  const float* hs   = (const float*)d_in[0];
  const float* in_w = (const float*)d_in[1];
  const float* cw   = (const float*)d_in[2];
  const float* cb   = (const float*)d_in[3];
  const float* xw   = (const float*)d_in[4];
  const float* dtw  = (const float*)d_in[5];
  const float* dtb  = (const float*)d_in[6];
  const float* alog = (const float*)d_in[7];
  const float* dsk  = (const float*)d_in[8];
  const float* ow   = (const float*)d_in[9];
  float* out = (float*)d_out;

  // ws layout (bytes) — total 234,881,024 == round-3 footprint
  char* ws = (char*)d_ws;
  float* x    = (float*)(ws);                                  // [M][384] fp32  50.33 MB
  float* u    = (float*)(ws + 50331648);                       // [M][384] fp32  50.33 MB
  float* xdbl = (float*)(ws + 100663296);                      // [M][64]  fp32   8.39 MB
  float* dt   = (float*)(ws + 109051904);                      // [M][384] fp32  50.33 MB
  float* Pbuf = (float*)(ws + 159383552);                      // 12.58 MB (h0)
  float* Sbuf = (float*)(ws + 171966464);                      // 12.58 MB
  unsigned short* zb = (unsigned short*)(ws + 184549376);      // [M][384] bf16  25.17 MB
  unsigned short* yb = (unsigned short*)(ws + 209715200);      // [M][384] bf16  25.17 MB
  // aliases in dead windows:
  unsigned short* hsb = (unsigned short*)Pbuf;  // [M][192] bf16 12.58 MB, dead after in_proj
  unsigned short* wb  = (unsigned short*)Sbuf;  // [768][192] bf16 294 KB, dead after in_proj
  float* wpad = Pbuf;                           // [64][384] fp32 98 KB, after in_proj, before scan1
  unsigned short* owb = (unsigned short*)Pbuf;  // [192][384] bf16 147 KB, after scan3

  // 1. casts + in_proj (bf16 MFMA, split epilogue: x fp32 / z bf16)
  castf2b<<<6144, 256, 0, stream>>>(hs, hsb, 1572864);
  castf2b<<<144, 256, 0, stream>>>(in_w, wb, 36864);
  gemm_bf16<DMODEL, true><<<dim3(12, 256), 256, 0, stream>>>(hsb, wb, x, zb, 768);
  // 2. depthwise conv + SiLU -> u
  conv_silu_k<<<(MTOT * DINNER) / 256, 256, 0, stream>>>(x, cw, cb, u);
  // 3. x_proj as padded fp32 GEMM (precision-critical: feeds dt/B/C)
  wpad_k<<<(XSTR * DINNER) / 256, 256, 0, stream>>>(xw, wpad);
  gemm2<DINNER><<<dim3(1, MTOT / 128), 256, 0, stream>>>(u, wpad, xdbl, XSTR);
  // 4. dt_proj + softplus (double bias per reference)
  dtproj_k<<<(MTOT * DINNER) / 256, 256, 0, stream>>>(xdbl, dtw, dtb, dt);
  // 5. chunked selective scan
  scan_part1<<<dim3(NC, BATCH), 384, 0, stream>>>(dt, u, xdbl, alog, Pbuf, Sbuf);
  scan_part2<<<(BATCH * DINNER * DSTATE) / 256, 256, 0, stream>>>(Pbuf, Sbuf);
  scan_part3<<<dim3(NC, BATCH), 384, 0, stream>>>(dt, u, xdbl, alog, dsk, zb, Pbuf, yb);
  // 6. out_proj (bf16 MFMA)
  castf2b<<<72, 256, 0, stream>>>(ow, owb, 18432);
  gemm_bf16<DINNER, false><<<dim3(3, 256), 256, 0, stream>>>(yb, owb, out, nullptr, 192);
}

// Round 6
// 295.121 us; speedup vs baseline: 12.1089x; 1.0555x over previous
//
#include <hip/hip_runtime.h>
#include <cmath>

#define BATCH 8
#define SEQLEN 4096
#define DMODEL 192
#define DINNER 384
#define DSTATE 16
#define DTRANK 12
#define XSTR 64            // padded x_dbl row stride (44 real cols)
#define MTOT (BATCH*SEQLEN)
#define CH 32              // scan chunk length
#define NC (SEQLEN/CH)     // 128 chunks

typedef __bf16 bf16x8 __attribute__((ext_vector_type(8)));
typedef float f32x4 __attribute__((ext_vector_type(4)));
typedef unsigned short us8 __attribute__((ext_vector_type(8)));

__device__ __forceinline__ float silu_f(float x) { return x / (1.f + __expf(-x)); }
__device__ __forceinline__ unsigned short f2bf(float f) {
  unsigned u = __float_as_uint(f);
  return (unsigned short)((u + 0x7FFF + ((u >> 16) & 1)) >> 16);   // RNE
}
__device__ __forceinline__ float bf2f(unsigned short b) {
  return __uint_as_float(((unsigned)b) << 16);
}

// a[n] = e1^(n+1), binary tree, depth 4
#define POW16(a, e1)                                                        \
  a[0] = (e1); a[1] = (e1) * (e1); a[2] = a[1] * (e1); a[3] = a[1] * a[1];  \
  a[4] = a[3] * (e1); a[5] = a[3] * a[1]; a[6] = a[3] * a[2];               \
  a[7] = a[3] * a[3]; a[8] = a[7] * (e1); a[9] = a[7] * a[1];               \
  a[10] = a[7] * a[2]; a[11] = a[7] * a[3]; a[12] = a[7] * a[4];            \
  a[13] = a[7] * a[5]; a[14] = a[7] * a[6]; a[15] = a[7] * a[7];

// fp32 -> bf16 cast, 4 elems/thread (weights only now)
__global__ __launch_bounds__(256) void castf2b(const float* __restrict__ src,
                                               unsigned short* __restrict__ dst, int n4) {
  const int i = blockIdx.x * 256 + threadIdx.x;
  if (i < n4) {
    float4 v = ((const float4*)src)[i];
    ushort4 o;
    o.x = f2bf(v.x); o.y = f2bf(v.y); o.z = f2bf(v.z); o.w = f2bf(v.w);
    ((ushort4*)dst)[i] = o;
  }
}

// bf16 MFMA GEMM: C[M][N] = A[M][K] @ W[N][K]^T, fp32 accum.
// BM=128, BN=64, BK=32; 4 waves (2m x 2n), each 64x32 = 4x2 frags of 16x16x32.
// AF32: A is fp32 in global, converted to bf16 during LDS staging (fused cast).
// SPLIT (in_proj): cols 0..383 -> Cx fp32 [M][384]; cols 384..767 -> Zb bf16 [M][384].
template<int K, bool SPLIT, bool AF32>
__global__ __launch_bounds__(256) void gemm_bf16(const void* __restrict__ A_,
                                                 const unsigned short* __restrict__ W,
                                                 float* __restrict__ Cx,
                                                 unsigned short* __restrict__ Zb,
                                                 int N) {
  __shared__ unsigned short Als[128 * 40];   // 80B rows: uniform bank spread
  __shared__ unsigned short Bls[64 * 40];
  const int tid = threadIdx.x;
  const int m0 = blockIdx.y * 128, n0 = blockIdx.x * 64;
  const int l = tid & 63;
  const int wm = ((tid >> 6) >> 1) * 64, wn = ((tid >> 6) & 1) * 32;
  const int lr = l & 15, lk8 = (l >> 4) * 8;
  const int ar = tid >> 1, ag = (tid & 1) * 16;    // A stage: row, elem offset
  const int br = tid >> 2, bg = (tid & 3) * 8;     // B stage
  const float* ApF = AF32 ? ((const float*)A_ + (size_t)(m0 + ar) * K + ag) : nullptr;
  const unsigned short* ApB = AF32 ? nullptr : ((const unsigned short*)A_ + (size_t)(m0 + ar) * K + ag);
  const unsigned short* Wp = W + (size_t)(n0 + br) * K + bg;
  f32x4 acc[4][2];
#pragma unroll
  for (int i = 0; i < 4; i++)
#pragma unroll
    for (int j = 0; j < 2; j++) acc[i][j] = (f32x4){0.f, 0.f, 0.f, 0.f};
  for (int k0 = 0; k0 < K; k0 += 32) {
    us8 a0, a1;
    if constexpr (AF32) {
      float4 f0 = *(const float4*)(ApF + k0);
      float4 f1 = *(const float4*)(ApF + k0 + 4);
      float4 f2 = *(const float4*)(ApF + k0 + 8);
      float4 f3 = *(const float4*)(ApF + k0 + 12);
      a0[0] = f2bf(f0.x); a0[1] = f2bf(f0.y); a0[2] = f2bf(f0.z); a0[3] = f2bf(f0.w);
      a0[4] = f2bf(f1.x); a0[5] = f2bf(f1.y); a0[6] = f2bf(f1.z); a0[7] = f2bf(f1.w);
      a1[0] = f2bf(f2.x); a1[1] = f2bf(f2.y); a1[2] = f2bf(f2.z); a1[3] = f2bf(f2.w);
      a1[4] = f2bf(f3.x); a1[5] = f2bf(f3.y); a1[6] = f2bf(f3.z); a1[7] = f2bf(f3.w);
    } else {
      a0 = *(const us8*)(ApB + k0);
      a1 = *(const us8*)(ApB + k0 + 8);
    }
    us8 bv = *(const us8*)(Wp + k0);
    __syncthreads();
    *(us8*)(&Als[ar * 40 + ag]) = a0;
    *(us8*)(&Als[ar * 40 + ag + 8]) = a1;
    *(us8*)(&Bls[br * 40 + bg]) = bv;
    __syncthreads();
    bf16x8 b0 = *(const bf16x8*)(&Bls[(wn + lr) * 40 + lk8]);
    bf16x8 b1 = *(const bf16x8*)(&Bls[(wn + 16 + lr) * 40 + lk8]);
#pragma unroll
    for (int fm = 0; fm < 4; fm++) {
      bf16x8 af = *(const bf16x8*)(&Als[(wm + fm * 16 + lr) * 40 + lk8]);
      acc[fm][0] = __builtin_amdgcn_mfma_f32_16x16x32_bf16(af, b0, acc[fm][0], 0, 0, 0);
      acc[fm][1] = __builtin_amdgcn_mfma_f32_16x16x32_bf16(af, b1, acc[fm][1], 0, 0, 0);
    }
  }
  const int r0 = (l >> 4) * 4;   // C/D: col=lane&15, row=(lane>>4)*4+reg (m89-verified)
#pragma unroll
  for (int fm = 0; fm < 4; fm++) {
    const size_t rowb = (size_t)(m0 + wm + fm * 16 + r0);
#pragma unroll
    for (int fn = 0; fn < 2; fn++) {
      const int col = n0 + wn + fn * 16 + lr;
      if constexpr (SPLIT) {
        if (col < DINNER) {
#pragma unroll
          for (int r = 0; r < 4; r++) Cx[(rowb + r) * DINNER + col] = acc[fm][fn][r];
        } else {
#pragma unroll
          for (int r = 0; r < 4; r++) Zb[(rowb + r) * DINNER + (col - DINNER)] = f2bf(acc[fm][fn][r]);
        }
      } else {
#pragma unroll
        for (int r = 0; r < 4; r++) Cx[(rowb + r) * N + col] = acc[fm][fn][r];
      }
    }
  }
}

// fp32 GEMM (kept for x_proj only — its outputs feed the scan, keep full precision)
template<int K>
__global__ __launch_bounds__(256) void gemm2(const float* __restrict__ A,
                                             const float* __restrict__ W,
                                             float* __restrict__ C, int N) {
  __shared__ float As[16 * 132];
  __shared__ float Ws[16 * 68];
  const int tid = threadIdx.x;
  const int m0 = blockIdx.y * 128, n0 = blockIdx.x * 64;
  const int lm = tid >> 1, lk = (tid & 1) * 8;
  const int wn = tid >> 2, wk = (tid & 3) * 4;
  const int ty = tid >> 4, tx = tid & 15;
  float acc[8][4] = {};
  const float* Ap = A + (size_t)(m0 + lm) * K + lk;
  const float* Wp = W + (size_t)(n0 + wn) * K + wk;
  for (int k0 = 0; k0 < K; k0 += 16) {
    float4 av0 = *(const float4*)(Ap + k0);
    float4 av1 = *(const float4*)(Ap + k0 + 4);
    float4 wv  = *(const float4*)(Wp + k0);
    __syncthreads();
    As[(lk + 0) * 132 + lm] = av0.x; As[(lk + 1) * 132 + lm] = av0.y;
    As[(lk + 2) * 132 + lm] = av0.z; As[(lk + 3) * 132 + lm] = av0.w;
    As[(lk + 4) * 132 + lm] = av1.x; As[(lk + 5) * 132 + lm] = av1.y;
    As[(lk + 6) * 132 + lm] = av1.z; As[(lk + 7) * 132 + lm] = av1.w;
    Ws[(wk + 0) * 68 + wn] = wv.x; Ws[(wk + 1) * 68 + wn] = wv.y;
    Ws[(wk + 2) * 68 + wn] = wv.z; Ws[(wk + 3) * 68 + wn] = wv.w;
    __syncthreads();
#pragma unroll
    for (int kk = 0; kk < 16; kk++) {
      float4 a0 = *(const float4*)&As[kk * 132 + ty * 8];
      float4 a1 = *(const float4*)&As[kk * 132 + ty * 8 + 4];
      float4 b  = *(const float4*)&Ws[kk * 68 + tx * 4];
      float ar[8] = {a0.x, a0.y, a0.z, a0.w, a1.x, a1.y, a1.z, a1.w};
      float br[4] = {b.x, b.y, b.z, b.w};
#pragma unroll
      for (int i = 0; i < 8; i++)
#pragma unroll
        for (int j = 0; j < 4; j++)
          acc[i][j] = fmaf(ar[i], br[j], acc[i][j]);
    }
  }
#pragma unroll
  for (int i = 0; i < 8; i++) {
    float4 o = make_float4(acc[i][0], acc[i][1], acc[i][2], acc[i][3]);
    *(float4*)(C + (size_t)(m0 + ty * 8 + i) * N + (n0 + tx * 4)) = o;
  }
}

// zero-pad x_proj_w [44][384] -> [64][384]
__global__ __launch_bounds__(256) void wpad_k(const float* __restrict__ xw,
                                              float* __restrict__ wp) {
  const int idx = blockIdx.x * 256 + threadIdx.x;
  const int r = idx / DINNER, c = idx % DINNER;
  wp[idx] = (r < 44) ? xw[r * DINNER + c] : 0.f;
}

// depthwise conv (k=3, same-pad) + SiLU; x is [M][384]
__global__ __launch_bounds__(256) void conv_silu_k(const float* __restrict__ x,
                                                   const float* __restrict__ cw,
                                                   const float* __restrict__ cb,
                                                   float* __restrict__ u) {
  const int idx = blockIdx.x * 256 + threadIdx.x;   // m*DINNER + d
  const int d = idx % DINNER;
  const int m = idx / DINNER;
  const int l = m % SEQLEN;
  const float w0 = cw[d * 3 + 0], w1 = cw[d * 3 + 1], w2 = cw[d * 3 + 2];
  float s = cb[d] + w1 * x[(size_t)m * DINNER + d];
  if (l > 0)          s += w0 * x[(size_t)(m - 1) * DINNER + d];
  if (l < SEQLEN - 1) s += w2 * x[(size_t)(m + 1) * DINNER + d];
  u[idx] = silu_f(s);
}

// dt[M][384] = softplus(x_dbl[:, :12] @ dt_proj_w^T + 2*dt_proj_b)  (ref adds bias twice)
__global__ __launch_bounds__(256) void dtproj_k(const float* __restrict__ xdbl,
                                                const float* __restrict__ dtw,
                                                const float* __restrict__ dtb,
                                                float* __restrict__ dt) {
  const int idx = blockIdx.x * 256 + threadIdx.x;
  const int d = idx % DINNER;
  const size_t m = idx / DINNER;
  const float* xr = xdbl + m * XSTR;
  const float* wr = dtw + d * DTRANK;
  float s = 2.f * dtb[d];
#pragma unroll
  for (int r = 0; r < DTRANK; r++) s = fmaf(xr[r], wr[r], s);
  dt[idx] = (s > 20.f) ? s : log1pf(__expf(s));
}

// ---- chunked parallel scan, thread-per-(b,d), 16 states in registers ----
// Fast path: A_log rows are log(1..16) (tiled) => exp(dt*A[n]) = exp(-dt)^(n+1):
// 1 exp + 15 full-rate muls replaces 16 quarter-rate exps. Runtime-checked.
__global__ __launch_bounds__(384, 6) void scan_part1(const float* __restrict__ dt,
                                                     const float* __restrict__ u,
                                                     const float* __restrict__ xdbl,
                                                     const float* __restrict__ A_log,
                                                     float* __restrict__ Pbuf,
                                                     float* __restrict__ Sbuf) {
  __shared__ float Bs[CH][DSTATE];            // 2 KB, broadcast reads
  const int d = threadIdx.x;
  const int c = blockIdx.x, b = blockIdx.y;
  const size_t mbase = (size_t)b * SEQLEN + (size_t)c * CH;
  if (d < CH * 4) {
    const int r = d >> 2, q = d & 3;
    float4 v = *(const float4*)(xdbl + (mbase + r) * XSTR + DTRANK + q * 4);
    float* dst = &Bs[r][q * 4];
    dst[0] = v.x; dst[1] = v.y; dst[2] = v.z; dst[3] = v.w;
  }
  float Av[DSTATE];
#pragma unroll
  for (int q = 0; q < 4; q++) {
    float4 v = *(const float4*)(A_log + d * DSTATE + q * 4);
    Av[q * 4 + 0] = -__expf(v.x); Av[q * 4 + 1] = -__expf(v.y);
    Av[q * 4 + 2] = -__expf(v.z); Av[q * 4 + 3] = -__expf(v.w);
  }
  bool fastp = true;
#pragma unroll
  for (int n = 0; n < DSTATE; n++)
    fastp = fastp && (fabsf(Av[n] + (float)(n + 1)) < 1e-5f * (float)(n + 1));
  float h[DSTATE];
#pragma unroll
  for (int n = 0; n < DSTATE; n++) h[n] = 0.f;
  float dtsum = 0.f;
  __syncthreads();
  float dtv = dt[mbase * DINNER + d];
  float uv  = u[mbase * DINNER + d];
  if (fastp) {
    for (int l = 0; l < CH; l++) {
      const int lp = (l + 1 < CH) ? (l + 1) : l;
      const float dtn = dt[(mbase + lp) * DINNER + d];
      const float un  = u[(mbase + lp) * DINNER + d];
      const float du = dtv * uv;
      dtsum += dtv;
      float a[DSTATE];
      const float e1 = __expf(-dtv);
      POW16(a, e1)
#pragma unroll
      for (int n = 0; n < DSTATE; n++)
        h[n] = fmaf(a[n], h[n], du * Bs[l][n]);
      dtv = dtn; uv = un;
    }
  } else {
    for (int l = 0; l < CH; l++) {
      const int lp = (l + 1 < CH) ? (l + 1) : l;
      const float dtn = dt[(mbase + lp) * DINNER + d];
      const float un  = u[(mbase + lp) * DINNER + d];
      const float du = dtv * uv;
      dtsum += dtv;
#pragma unroll
      for (int n = 0; n < DSTATE; n++) {
        const float a = __expf(dtv * Av[n]);
        h[n] = fmaf(a, h[n], du * Bs[l][n]);
      }
      dtv = dtn; uv = un;
    }
  }
  float P[DSTATE];
  if (fastp) {
    const float ep = __expf(-dtsum);
    POW16(P, ep)
  } else {
#pragma unroll
    for (int n = 0; n < DSTATE; n++) P[n] = __expf(dtsum * Av[n]);
  }
  float* Pp = Pbuf + ((size_t)(b * NC + c) * DINNER + d) * DSTATE;
  float* Sp = Sbuf + ((size_t)(b * NC + c) * DINNER + d) * DSTATE;
#pragma unroll
  for (int q = 0; q < 4; q++) {
    float4 pv, sv;
    pv.x = P[q * 4 + 0]; pv.y = P[q * 4 + 1]; pv.z = P[q * 4 + 2]; pv.w = P[q * 4 + 3];
    sv.x = h[q * 4 + 0]; sv.y = h[q * 4 + 1]; sv.z = h[q * 4 + 2]; sv.w = h[q * 4 + 3];
    *(float4*)(Pp + q * 4) = pv;
    *(float4*)(Sp + q * 4) = sv;
  }
}

__global__ __launch_bounds__(256) void scan_part2(float* __restrict__ Pbuf,
                                                  const float* __restrict__ Sbuf) {
  const int i = blockIdx.x * 256 + threadIdx.x;
  const int b = i / (DINNER * DSTATE);
  const int r = i % (DINNER * DSTATE);
  float h = 0.f;
  for (int c = 0; c < NC; c++) {
    const size_t idx = (size_t)(b * NC + c) * (DINNER * DSTATE) + r;
    const float p = Pbuf[idx], s = Sbuf[idx];
    Pbuf[idx] = h;
    h = fmaf(p, h, s);
  }
}

// Pass 3: re-run from h0; y = (h.C + D*u)*silu(z) emitted as bf16 for out_proj.
__global__ __launch_bounds__(384, 6) void scan_part3(const float* __restrict__ dt,
                                                     const float* __restrict__ u,
                                                     const float* __restrict__ xdbl,
                                                     const float* __restrict__ A_log,
                                                     const float* __restrict__ Dsk,
                                                     const unsigned short* __restrict__ zb,
                                                     const float* __restrict__ H0,
                                                     unsigned short* __restrict__ yb) {
  __shared__ float BC[CH][2 * DSTATE];        // 4 KB: [l][0..15]=B, [l][16..31]=C
  const int d = threadIdx.x;
  const int c = blockIdx.x, b = blockIdx.y;
  const size_t mbase = (size_t)b * SEQLEN + (size_t)c * CH;
  for (int i = d; i < CH * 8; i += 384) {
    const int r = i >> 3, q = i & 7;
    float4 v = *(const float4*)(xdbl + (mbase + r) * XSTR + DTRANK + q * 4);
    float* dst = &BC[r][q * 4];
    dst[0] = v.x; dst[1] = v.y; dst[2] = v.z; dst[3] = v.w;
  }
  float Av[DSTATE];
#pragma unroll
  for (int q = 0; q < 4; q++) {
    float4 v = *(const float4*)(A_log + d * DSTATE + q * 4);
    Av[q * 4 + 0] = -__expf(v.x); Av[q * 4 + 1] = -__expf(v.y);
    Av[q * 4 + 2] = -__expf(v.z); Av[q * 4 + 3] = -__expf(v.w);
  }
  bool fastp = true;
#pragma unroll
  for (int n = 0; n < DSTATE; n++)
    fastp = fastp && (fabsf(Av[n] + (float)(n + 1)) < 1e-5f * (float)(n + 1));
  const float Dv = Dsk[d];
  float h[DSTATE];
  {
    const float* Hp = H0 + ((size_t)(b * NC + c) * DINNER + d) * DSTATE;
#pragma unroll
    for (int q = 0; q < 4; q++) {
      float4 v = *(const float4*)(Hp + q * 4);
      h[q * 4 + 0] = v.x; h[q * 4 + 1] = v.y; h[q * 4 + 2] = v.z; h[q * 4 + 3] = v.w;
    }
  }
  __syncthreads();
  float dtv = dt[mbase * DINNER + d];
  float uv  = u[mbase * DINNER + d];
  float zv  = bf2f(zb[mbase * DINNER + d]);
  if (fastp) {
    for (int l = 0; l < CH; l++) {
      const int lp = (l + 1 < CH) ? (l + 1) : l;
      const float dtn = dt[(mbase + lp) * DINNER + d];
      const float un  = u[(mbase + lp) * DINNER + d];
      const float zn  = bf2f(zb[(mbase + lp) * DINNER + d]);
      const float du = dtv * uv;
      float yacc = Dv * uv;
      float a[DSTATE];
      const float e1 = __expf(-dtv);
      POW16(a, e1)
#pragma unroll
      for (int n = 0; n < DSTATE; n++) {
        h[n] = fmaf(a[n], h[n], du * BC[l][n]);
        yacc = fmaf(h[n], BC[l][DSTATE + n], yacc);
      }
      yb[(mbase + l) * DINNER + d] = f2bf(yacc * silu_f(zv));
      dtv = dtn; uv = un; zv = zn;
    }
  } else {
    for (int l = 0; l < CH; l++) {
      const int lp = (l + 1 < CH) ? (l + 1) : l;
      const float dtn = dt[(mbase + lp) * DINNER + d];
      const float un  = u[(mbase + lp) * DINNER + d];
      const float zn  = bf2f(zb[(mbase + lp) * DINNER + d]);
      const float du = dtv * uv;
      float yacc = Dv * uv;
#pragma unroll
      for (int n = 0; n < DSTATE; n++) {
        const float a = __expf(dtv * Av[n]);
        h[n] = fmaf(a, h[n], du * BC[l][n]);
        yacc = fmaf(h[n], BC[l][DSTATE + n], yacc);
      }
      yb[(mbase + l) * DINNER + d] = f2bf(yacc * silu_f(zv));
      dtv = dtn; uv = un; zv = zn;
    }
  }
}

extern "C" void kernel_launch(void* const* d_in, const int* in_sizes, int n_in,
                              void* d_out, int out_size, void* d_ws, size_t ws_size,
                              hipStream_t stream) {
  const float* hs   = (const float*)d_in[0];
  const float* in_w = (const float*)d_in[1];
  const float* cw   = (const float*)d_in[2];
  const float* cb   = (const float*)d_in[3];
  const float* xw   = (const float*)d_in[4];
  const float* dtw  = (const float*)d_in[5];
  const float* dtb  = (const float*)d_in[6];
  const float* alog = (const float*)d_in[7];
  const float* dsk  = (const float*)d_in[8];
  const float* ow   = (const float*)d_in[9];
  float* out = (float*)d_out;

  // ws layout (bytes) — total 234,881,024 (same as round 4)
  char* ws = (char*)d_ws;
  float* x    = (float*)(ws);                                  // [M][384] fp32 50.33 MB (dead after conv)
  float* u    = (float*)(ws + 50331648);                       // [M][384] fp32 50.33 MB
  float* xdbl = (float*)(ws + 100663296);                      // [M][64]  fp32  8.39 MB
  float* dt   = (float*)(ws + 109051904);                      // [M][384] fp32 50.33 MB
  float* Pbuf = (float*)(ws + 159383552);                      // [B][128][D][N] 25.17 MB (h0)
  float* Sbuf = (float*)(ws + 184549376);                      // 25.17 MB
  unsigned short* zb = (unsigned short*)(ws + 209715200);      // [M][384] bf16 25.17 MB
  // aliases in dead windows:
  unsigned short* yb  = (unsigned short*)x;     // [M][384] bf16 25.17 MB over dead x (part3 -> out_proj)
  unsigned short* wb  = (unsigned short*)Pbuf;  // [768][192] bf16 294 KB, dead before part1
  float* wpad = Sbuf;                           // [64][384] fp32 98 KB, dead before part1
  unsigned short* owb = (unsigned short*)Pbuf;  // [192][384] bf16 147 KB, after part3 reads H0

  // 1. in_proj (bf16 MFMA, A-cast fused into staging; split epilogue: x fp32 / z bf16)
  castf2b<<<144, 256, 0, stream>>>(in_w, wb, 36864);
  gemm_bf16<DMODEL, true, true><<<dim3(12, 256), 256, 0, stream>>>(hs, wb, x, zb, 768);
  // 2. depthwise conv + SiLU -> u
  conv_silu_k<<<(MTOT * DINNER) / 256, 256, 0, stream>>>(x, cw, cb, u);
  // 3. x_proj as padded fp32 GEMM (precision-critical: feeds dt/B/C)
  wpad_k<<<(XSTR * DINNER) / 256, 256, 0, stream>>>(xw, wpad);
  gemm2<DINNER><<<dim3(1, MTOT / 128), 256, 0, stream>>>(u, wpad, xdbl, XSTR);
  // 4. dt_proj + softplus (double bias per reference)
  dtproj_k<<<(MTOT * DINNER) / 256, 256, 0, stream>>>(xdbl, dtw, dtb, dt);
  // 5. chunked selective scan (CH=32 -> 1024 blocks, 6 waves/SIMD)
  scan_part1<<<dim3(NC, BATCH), 384, 0, stream>>>(dt, u, xdbl, alog, Pbuf, Sbuf);
  scan_part2<<<(BATCH * DINNER * DSTATE) / 256, 256, 0, stream>>>(Pbuf, Sbuf);
  scan_part3<<<dim3(NC, BATCH), 384, 0, stream>>>(dt, u, xdbl, alog, dsk, zb, Pbuf, yb);
  // 6. out_proj (bf16 MFMA)
  castf2b<<<72, 256, 0, stream>>>(ow, owb, 18432);
  gemm_bf16<DINNER, false, false><<<dim3(3, 256), 256, 0, stream>>>(yb, owb, out, nullptr, 192);
}

// Round 7
// 234.567 us; speedup vs baseline: 15.2348x; 1.2582x over previous
//
#include <hip/hip_runtime.h>
#include <cmath>

#define BATCH 8
#define SEQLEN 4096
#define DMODEL 192
#define DINNER 384
#define DSTATE 16
#define DTRANK 12
#define XSTR 64            // padded x_dbl row stride (44 real cols)
#define MTOT (BATCH*SEQLEN)
#define CH 32              // scan chunk length
#define NC (SEQLEN/CH)     // 128 chunks

typedef __bf16 bf16x8 __attribute__((ext_vector_type(8)));
typedef float f32x4 __attribute__((ext_vector_type(4)));
typedef unsigned short us8 __attribute__((ext_vector_type(8)));

__device__ __forceinline__ float silu_f(float x) { return x / (1.f + __expf(-x)); }
__device__ __forceinline__ unsigned short f2bf(float f) {
  unsigned u = __float_as_uint(f);
  return (unsigned short)((u + 0x7FFF + ((u >> 16) & 1)) >> 16);   // RNE
}
__device__ __forceinline__ float bf2f(unsigned short b) {
  return __uint_as_float(((unsigned)b) << 16);
}

// a[n] = e1^(n+1), binary tree, depth 4
#define POW16(a, e1)                                                        \
  a[0] = (e1); a[1] = (e1) * (e1); a[2] = a[1] * (e1); a[3] = a[1] * a[1];  \
  a[4] = a[3] * (e1); a[5] = a[3] * a[1]; a[6] = a[3] * a[2];               \
  a[7] = a[3] * a[3]; a[8] = a[7] * (e1); a[9] = a[7] * a[1];               \
  a[10] = a[7] * a[2]; a[11] = a[7] * a[3]; a[12] = a[7] * a[4];            \
  a[13] = a[7] * a[5]; a[14] = a[7] * a[6]; a[15] = a[7] * a[7];

// single prep kernel: cast in_proj_w, pad+cast x_proj_w, cast out_proj_w
__global__ __launch_bounds__(256) void prep_k(const float* __restrict__ in_w,
                                              const float* __restrict__ xw,
                                              const float* __restrict__ ow,
                                              unsigned short* __restrict__ wb,
                                              unsigned short* __restrict__ wxb,
                                              unsigned short* __restrict__ owb) {
  const int i = blockIdx.x * 256 + threadIdx.x;
  if (i < 768 * DMODEL) wb[i] = f2bf(in_w[i]);
  if (i < XSTR * DINNER) wxb[i] = (i < 44 * DINNER) ? f2bf(xw[i]) : (unsigned short)0;
  if (i < DMODEL * DINNER) owb[i] = f2bf(ow[i]);
}

// in_proj: [M][768] = hs[M][192] @ in_w^T. BM=128 BN=128 BK=32, 4 waves (2x2),
// wave 64x64 = 4x4 frags. XCD-chunked swizzle: each XCD owns 32 m-panels x all
// 6 n-blocks -> A panel fetched by exactly one XCD L2. Outputs bf16 (x | z).
__global__ __launch_bounds__(256) void gemm_in(const float* __restrict__ hs,
                                               const unsigned short* __restrict__ wb,
                                               unsigned short* __restrict__ xb,
                                               unsigned short* __restrict__ zb) {
  __shared__ unsigned short Als[128 * 40];   // 80B rows
  __shared__ unsigned short Bls[128 * 40];
  const int tid = threadIdx.x;
  const int bid = blockIdx.y * 6 + blockIdx.x;        // 0..1535
  const int lid = (bid & 7) * 192 + (bid >> 3);       // bijective (1536%8==0)
  const int m0 = (lid / 6) * 128, n0 = (lid % 6) * 128;
  const int w = tid >> 6, l = tid & 63;
  const int wm = (w >> 1) * 64, wn = (w & 1) * 64;
  const int lr = l & 15, lk8 = (l >> 4) * 8;
  const int ar = tid >> 1, ag = (tid & 1) * 16;
  const float* Ap = hs + (size_t)(m0 + ar) * DMODEL + ag;
  const unsigned short* Wp = wb + (size_t)(n0 + ar) * DMODEL + ag;
  f32x4 acc[4][4];
#pragma unroll
  for (int i = 0; i < 4; i++)
#pragma unroll
    for (int j = 0; j < 4; j++) acc[i][j] = (f32x4){0.f, 0.f, 0.f, 0.f};
#pragma unroll
  for (int k0 = 0; k0 < DMODEL; k0 += 32) {
    float4 f0 = *(const float4*)(Ap + k0);
    float4 f1 = *(const float4*)(Ap + k0 + 4);
    float4 f2 = *(const float4*)(Ap + k0 + 8);
    float4 f3 = *(const float4*)(Ap + k0 + 12);
    us8 b0 = *(const us8*)(Wp + k0);
    us8 b1 = *(const us8*)(Wp + k0 + 8);
    us8 a0, a1;
    a0[0] = f2bf(f0.x); a0[1] = f2bf(f0.y); a0[2] = f2bf(f0.z); a0[3] = f2bf(f0.w);
    a0[4] = f2bf(f1.x); a0[5] = f2bf(f1.y); a0[6] = f2bf(f1.z); a0[7] = f2bf(f1.w);
    a1[0] = f2bf(f2.x); a1[1] = f2bf(f2.y); a1[2] = f2bf(f2.z); a1[3] = f2bf(f2.w);
    a1[4] = f2bf(f3.x); a1[5] = f2bf(f3.y); a1[6] = f2bf(f3.z); a1[7] = f2bf(f3.w);
    __syncthreads();
    *(us8*)(&Als[ar * 40 + ag]) = a0;
    *(us8*)(&Als[ar * 40 + ag + 8]) = a1;
    *(us8*)(&Bls[ar * 40 + ag]) = b0;
    *(us8*)(&Bls[ar * 40 + ag + 8]) = b1;
    __syncthreads();
    bf16x8 bfr[4];
#pragma unroll
    for (int fn = 0; fn < 4; fn++)
      bfr[fn] = *(const bf16x8*)(&Bls[(wn + fn * 16 + lr) * 40 + lk8]);
#pragma unroll
    for (int fm = 0; fm < 4; fm++) {
      bf16x8 af = *(const bf16x8*)(&Als[(wm + fm * 16 + lr) * 40 + lk8]);
#pragma unroll
      for (int fn = 0; fn < 4; fn++)
        acc[fm][fn] = __builtin_amdgcn_mfma_f32_16x16x32_bf16(af, bfr[fn], acc[fm][fn], 0, 0, 0);
    }
  }
  const int r0 = (l >> 4) * 4;   // C/D: col=lane&15, row=(lane>>4)*4+reg
  unsigned short* dst = (n0 < DINNER) ? xb : zb;
  const int cb0 = (n0 < DINNER) ? n0 : (n0 - DINNER);
#pragma unroll
  for (int fm = 0; fm < 4; fm++) {
    const size_t rowb = (size_t)(m0 + wm + fm * 16 + r0);
#pragma unroll
    for (int fn = 0; fn < 4; fn++) {
      const int col = cb0 + wn + fn * 16 + lr;
#pragma unroll
      for (int r = 0; r < 4; r++)
        dst[(rowb + r) * DINNER + col] = f2bf(acc[fm][fn][r]);
    }
  }
}

// depthwise conv (k=3, same-pad) + SiLU, bf16 in/out, 8 channels/thread
__global__ __launch_bounds__(256) void conv_silu_k(const unsigned short* __restrict__ xb,
                                                   const float* __restrict__ cw,
                                                   const float* __restrict__ cb,
                                                   unsigned short* __restrict__ u16) {
  __shared__ float cws[DINNER * 4];   // [0..3*384) = cw, [3*384..) = cb
  const int tid = threadIdx.x;
  for (int i = tid; i < DINNER * 4; i += 256)
    cws[i] = (i < DINNER * 3) ? cw[i] : cb[i - DINNER * 3];
  __syncthreads();
  const int idx = blockIdx.x * 256 + tid;
  const int d = (idx % 48) * 8;
  const int m = idx / 48;
  const int l = m % SEQLEN;
  const us8 c0 = *(const us8*)(xb + (size_t)m * DINNER + d);
  const bool hm = (l > 0), hp = (l < SEQLEN - 1);
  us8 cm = c0, cp = c0;
  if (hm) cm = *(const us8*)(xb + (size_t)(m - 1) * DINNER + d);
  if (hp) cp = *(const us8*)(xb + (size_t)(m + 1) * DINNER + d);
  us8 o;
#pragma unroll
  for (int j = 0; j < 8; j++) {
    const int dj = d + j;
    float s = cws[DINNER * 3 + dj] + cws[dj * 3 + 1] * bf2f(c0[j]);
    if (hm) s += cws[dj * 3 + 0] * bf2f(cm[j]);
    if (hp) s += cws[dj * 3 + 2] * bf2f(cp[j]);
    o[j] = f2bf(silu_f(s));
  }
  *(us8*)(u16 + (size_t)m * DINNER + d) = o;
}

// x_proj: xdbl[M][64] fp32 = u16[M][384] @ wxb[64][384]^T (bf16 MFMA, fp32 acc)
// BM=64 BN=64 BK=32, 4 waves (2x2), wave 32x32 = 2x2 frags. grid 512 -> 2 w/SIMD.
__global__ __launch_bounds__(256) void xproj_mfma(const unsigned short* __restrict__ u16,
                                                  const unsigned short* __restrict__ wxb,
                                                  float* __restrict__ xdbl) {
  __shared__ unsigned short Als[64 * 40];
  __shared__ unsigned short Bls[64 * 40];
  const int tid = threadIdx.x;
  const int m0 = blockIdx.x * 64;
  const int w = tid >> 6, l = tid & 63;
  const int wm = (w >> 1) * 32, wn = (w & 1) * 32;
  const int lr = l & 15, lk8 = (l >> 4) * 8;
  const int ar = tid >> 2, ag = (tid & 3) * 8;
  const unsigned short* Ap = u16 + (size_t)(m0 + ar) * DINNER + ag;
  const unsigned short* Wp = wxb + (size_t)ar * DINNER + ag;
  f32x4 acc[2][2];
#pragma unroll
  for (int i = 0; i < 2; i++)
#pragma unroll
    for (int j = 0; j < 2; j++) acc[i][j] = (f32x4){0.f, 0.f, 0.f, 0.f};
#pragma unroll
  for (int k0 = 0; k0 < DINNER; k0 += 32) {
    us8 a0 = *(const us8*)(Ap + k0);
    us8 b0 = *(const us8*)(Wp + k0);
    __syncthreads();
    *(us8*)(&Als[ar * 40 + ag]) = a0;
    *(us8*)(&Bls[ar * 40 + ag]) = b0;
    __syncthreads();
    bf16x8 bf0 = *(const bf16x8*)(&Bls[(wn + lr) * 40 + lk8]);
    bf16x8 bf1 = *(const bf16x8*)(&Bls[(wn + 16 + lr) * 40 + lk8]);
#pragma unroll
    for (int fm = 0; fm < 2; fm++) {
      bf16x8 af = *(const bf16x8*)(&Als[(wm + fm * 16 + lr) * 40 + lk8]);
      acc[fm][0] = __builtin_amdgcn_mfma_f32_16x16x32_bf16(af, bf0, acc[fm][0], 0, 0, 0);
      acc[fm][1] = __builtin_amdgcn_mfma_f32_16x16x32_bf16(af, bf1, acc[fm][1], 0, 0, 0);
    }
  }
  const int r0 = (l >> 4) * 4;
#pragma unroll
  for (int fm = 0; fm < 2; fm++) {
    const size_t rowb = (size_t)(m0 + wm + fm * 16 + r0);
#pragma unroll
    for (int fn = 0; fn < 2; fn++) {
      const int col = wn + fn * 16 + lr;
#pragma unroll
      for (int r = 0; r < 4; r++)
        xdbl[(rowb + r) * XSTR + col] = acc[fm][fn][r];
    }
  }
}

// dt[M][384] = softplus(x_dbl[:, :12] @ dt_proj_w^T + 2*dt_proj_b), 4 d/thread
__global__ __launch_bounds__(256) void dtproj_k(const float* __restrict__ xdbl,
                                                const float* __restrict__ dtw,
                                                const float* __restrict__ dtb,
                                                float* __restrict__ dt) {
  const int idx = blockIdx.x * 256 + threadIdx.x;
  const int q = (idx % 96) * 4;
  const size_t m = idx / 96;
  const float* xr = xdbl + m * XSTR;
  float xs[12];
  *(float4*)(xs) = *(const float4*)(xr);
  *(float4*)(xs + 4) = *(const float4*)(xr + 4);
  *(float4*)(xs + 8) = *(const float4*)(xr + 8);
  float4 o;
#pragma unroll
  for (int t = 0; t < 4; t++) {
    const int dd = q + t;
    const float* wr = dtw + dd * DTRANK;
    float s = 2.f * dtb[dd];
#pragma unroll
    for (int r = 0; r < DTRANK; r++) s = fmaf(xs[r], wr[r], s);
    ((float*)&o)[t] = (s > 20.f) ? s : log1pf(__expf(s));
  }
  *(float4*)(dt + m * DINNER + q) = o;
}

// ---- chunked parallel scan, thread-per-(b,d), 16 states in registers ----
__global__ __launch_bounds__(384, 6) void scan_part1(const float* __restrict__ dt,
                                                     const unsigned short* __restrict__ u16,
                                                     const float* __restrict__ xdbl,
                                                     const float* __restrict__ A_log,
                                                     float* __restrict__ Pbuf,
                                                     float* __restrict__ Sbuf) {
  __shared__ float Bs[CH][DSTATE];
  const int d = threadIdx.x;
  const int c = blockIdx.x, b = blockIdx.y;
  const size_t mbase = (size_t)b * SEQLEN + (size_t)c * CH;
  if (d < CH * 4) {
    const int r = d >> 2, q = d & 3;
    float4 v = *(const float4*)(xdbl + (mbase + r) * XSTR + DTRANK + q * 4);
    float* dst = &Bs[r][q * 4];
    dst[0] = v.x; dst[1] = v.y; dst[2] = v.z; dst[3] = v.w;
  }
  float Av[DSTATE];
#pragma unroll
  for (int q = 0; q < 4; q++) {
    float4 v = *(const float4*)(A_log + d * DSTATE + q * 4);
    Av[q * 4 + 0] = -__expf(v.x); Av[q * 4 + 1] = -__expf(v.y);
    Av[q * 4 + 2] = -__expf(v.z); Av[q * 4 + 3] = -__expf(v.w);
  }
  bool fastp = true;
#pragma unroll
  for (int n = 0; n < DSTATE; n++)
    fastp = fastp && (fabsf(Av[n] + (float)(n + 1)) < 1e-5f * (float)(n + 1));
  float h[DSTATE];
#pragma unroll
  for (int n = 0; n < DSTATE; n++) h[n] = 0.f;
  float dtsum = 0.f;
  __syncthreads();
  float dtv = dt[mbase * DINNER + d];
  float uv  = bf2f(u16[mbase * DINNER + d]);
  if (fastp) {
    for (int l = 0; l < CH; l++) {
      const int lp = (l + 1 < CH) ? (l + 1) : l;
      const float dtn = dt[(mbase + lp) * DINNER + d];
      const float un  = bf2f(u16[(mbase + lp) * DINNER + d]);
      const float du = dtv * uv;
      dtsum += dtv;
      float a[DSTATE];
      const float e1 = __expf(-dtv);
      POW16(a, e1)
#pragma unroll
      for (int n = 0; n < DSTATE; n++)
        h[n] = fmaf(a[n], h[n], du * Bs[l][n]);
      dtv = dtn; uv = un;
    }
  } else {
    for (int l = 0; l < CH; l++) {
      const int lp = (l + 1 < CH) ? (l + 1) : l;
      const float dtn = dt[(mbase + lp) * DINNER + d];
      const float un  = bf2f(u16[(mbase + lp) * DINNER + d]);
      const float du = dtv * uv;
      dtsum += dtv;
#pragma unroll
      for (int n = 0; n < DSTATE; n++) {
        const float a = __expf(dtv * Av[n]);
        h[n] = fmaf(a, h[n], du * Bs[l][n]);
      }
      dtv = dtn; uv = un;
    }
  }
  float P[DSTATE];
  if (fastp) {
    const float ep = __expf(-dtsum);
    POW16(P, ep)
  } else {
#pragma unroll
    for (int n = 0; n < DSTATE; n++) P[n] = __expf(dtsum * Av[n]);
  }
  float* Pp = Pbuf + ((size_t)(b * NC + c) * DINNER + d) * DSTATE;
  float* Sp = Sbuf + ((size_t)(b * NC + c) * DINNER + d) * DSTATE;
#pragma unroll
  for (int q = 0; q < 4; q++) {
    float4 pv, sv;
    pv.x = P[q * 4 + 0]; pv.y = P[q * 4 + 1]; pv.z = P[q * 4 + 2]; pv.w = P[q * 4 + 3];
    sv.x = h[q * 4 + 0]; sv.y = h[q * 4 + 1]; sv.z = h[q * 4 + 2]; sv.w = h[q * 4 + 3];
    *(float4*)(Pp + q * 4) = pv;
    *(float4*)(Sp + q * 4) = sv;
  }
}

__global__ __launch_bounds__(256) void scan_part2(float* __restrict__ Pbuf,
                                                  const float* __restrict__ Sbuf) {
  const int i = blockIdx.x * 256 + threadIdx.x;
  const int b = i / (DINNER * DSTATE);
  const int r = i % (DINNER * DSTATE);
  float h = 0.f;
  for (int c = 0; c < NC; c++) {
    const size_t idx = (size_t)(b * NC + c) * (DINNER * DSTATE) + r;
    const float p = Pbuf[idx], s = Sbuf[idx];
    Pbuf[idx] = h;
    h = fmaf(p, h, s);
  }
}

// Pass 3: re-run from h0; y = (h.C + D*u)*silu(z) emitted bf16 for out_proj.
__global__ __launch_bounds__(384, 6) void scan_part3(const float* __restrict__ dt,
                                                     const unsigned short* __restrict__ u16,
                                                     const float* __restrict__ xdbl,
                                                     const float* __restrict__ A_log,
                                                     const float* __restrict__ Dsk,
                                                     const unsigned short* __restrict__ zb,
                                                     const float* __restrict__ H0,
                                                     unsigned short* __restrict__ yb) {
  __shared__ float BC[CH][2 * DSTATE];
  const int d = threadIdx.x;
  const int c = blockIdx.x, b = blockIdx.y;
  const size_t mbase = (size_t)b * SEQLEN + (size_t)c * CH;
  for (int i = d; i < CH * 8; i += 384) {
    const int r = i >> 3, q = i & 7;
    float4 v = *(const float4*)(xdbl + (mbase + r) * XSTR + DTRANK + q * 4);
    float* dst = &BC[r][q * 4];
    dst[0] = v.x; dst[1] = v.y; dst[2] = v.z; dst[3] = v.w;
  }
  float Av[DSTATE];
#pragma unroll
  for (int q = 0; q < 4; q++) {
    float4 v = *(const float4*)(A_log + d * DSTATE + q * 4);
    Av[q * 4 + 0] = -__expf(v.x); Av[q * 4 + 1] = -__expf(v.y);
    Av[q * 4 + 2] = -__expf(v.z); Av[q * 4 + 3] = -__expf(v.w);
  }
  bool fastp = true;
#pragma unroll
  for (int n = 0; n < DSTATE; n++)
    fastp = fastp && (fabsf(Av[n] + (float)(n + 1)) < 1e-5f * (float)(n + 1));
  const float Dv = Dsk[d];
  float h[DSTATE];
  {
    const float* Hp = H0 + ((size_t)(b * NC + c) * DINNER + d) * DSTATE;
#pragma unroll
    for (int q = 0; q < 4; q++) {
      float4 v = *(const float4*)(Hp + q * 4);
      h[q * 4 + 0] = v.x; h[q * 4 + 1] = v.y; h[q * 4 + 2] = v.z; h[q * 4 + 3] = v.w;
    }
  }
  __syncthreads();
  float dtv = dt[mbase * DINNER + d];
  float uv  = bf2f(u16[mbase * DINNER + d]);
  float zv  = bf2f(zb[mbase * DINNER + d]);
  if (fastp) {
    for (int l = 0; l < CH; l++) {
      const int lp = (l + 1 < CH) ? (l + 1) : l;
      const float dtn = dt[(mbase + lp) * DINNER + d];
      const float un  = bf2f(u16[(mbase + lp) * DINNER + d]);
      const float zn  = bf2f(zb[(mbase + lp) * DINNER + d]);
      const float du = dtv * uv;
      float yacc = Dv * uv;
      float a[DSTATE];
      const float e1 = __expf(-dtv);
      POW16(a, e1)
#pragma unroll
      for (int n = 0; n < DSTATE; n++) {
        h[n] = fmaf(a[n], h[n], du * BC[l][n]);
        yacc = fmaf(h[n], BC[l][DSTATE + n], yacc);
      }
      yb[(mbase + l) * DINNER + d] = f2bf(yacc * silu_f(zv));
      dtv = dtn; uv = un; zv = zn;
    }
  } else {
    for (int l = 0; l < CH; l++) {
      const int lp = (l + 1 < CH) ? (l + 1) : l;
      const float dtn = dt[(mbase + lp) * DINNER + d];
      const float un  = bf2f(u16[(mbase + lp) * DINNER + d]);
      const float zn  = bf2f(zb[(mbase + lp) * DINNER + d]);
      const float du = dtv * uv;
      float yacc = Dv * uv;
#pragma unroll
      for (int n = 0; n < DSTATE; n++) {
        const float a = __expf(dtv * Av[n]);
        h[n] = fmaf(a, h[n], du * BC[l][n]);
        yacc = fmaf(h[n], BC[l][DSTATE + n], yacc);
      }
      yb[(mbase + l) * DINNER + d] = f2bf(yacc * silu_f(zv));
      dtv = dtn; uv = un; zv = zn;
    }
  }
}

// out_proj: out[M][192] fp32 = yb[M][384] @ ow^T. BM=128 BN=64 BK=32, XCD swizzle.
__global__ __launch_bounds__(256) void gemm_out(const unsigned short* __restrict__ yb,
                                                const unsigned short* __restrict__ owb,
                                                float* __restrict__ out) {
  __shared__ unsigned short Als[128 * 40];
  __shared__ unsigned short Bls[64 * 40];
  const int tid = threadIdx.x;
  const int bid = blockIdx.y * 3 + blockIdx.x;        // 0..767
  const int lid = (bid & 7) * 96 + (bid >> 3);        // bijective (768%8==0)
  const int m0 = (lid / 3) * 128, n0 = (lid % 3) * 64;
  const int w = tid >> 6, l = tid & 63;
  const int wm = (w >> 1) * 64, wn = (w & 1) * 32;
  const int lr = l & 15, lk8 = (l >> 4) * 8;
  const int ar = tid >> 1, ag = (tid & 1) * 16;
  const int br = tid >> 2, bg = (tid & 3) * 8;
  const unsigned short* Ap = yb + (size_t)(m0 + ar) * DINNER + ag;
  const unsigned short* Wp = owb + (size_t)(n0 + br) * DINNER + bg;
  f32x4 acc[4][2];
#pragma unroll
  for (int i = 0; i < 4; i++)
#pragma unroll
    for (int j = 0; j < 2; j++) acc[i][j] = (f32x4){0.f, 0.f, 0.f, 0.f};
#pragma unroll
  for (int k0 = 0; k0 < DINNER; k0 += 32) {
    us8 a0 = *(const us8*)(Ap + k0);
    us8 a1 = *(const us8*)(Ap + k0 + 8);
    us8 bv = *(const us8*)(Wp + k0);
    __syncthreads();
    *(us8*)(&Als[ar * 40 + ag]) = a0;
    *(us8*)(&Als[ar * 40 + ag + 8]) = a1;
    *(us8*)(&Bls[br * 40 + bg]) = bv;
    __syncthreads();
    bf16x8 b0 = *(const bf16x8*)(&Bls[(wn + lr) * 40 + lk8]);
    bf16x8 b1 = *(const bf16x8*)(&Bls[(wn + 16 + lr) * 40 + lk8]);
#pragma unroll
    for (int fm = 0; fm < 4; fm++) {
      bf16x8 af = *(const bf16x8*)(&Als[(wm + fm * 16 + lr) * 40 + lk8]);
      acc[fm][0] = __builtin_amdgcn_mfma_f32_16x16x32_bf16(af, b0, acc[fm][0], 0, 0, 0);
      acc[fm][1] = __builtin_amdgcn_mfma_f32_16x16x32_bf16(af, b1, acc[fm][1], 0, 0, 0);
    }
  }
  const int r0 = (l >> 4) * 4;
#pragma unroll
  for (int fm = 0; fm < 4; fm++) {
    const size_t rowb = (size_t)(m0 + wm + fm * 16 + r0);
#pragma unroll
    for (int fn = 0; fn < 2; fn++) {
      const int col = n0 + wn + fn * 16 + lr;
#pragma unroll
      for (int r = 0; r < 4; r++)
        out[(rowb + r) * DMODEL + col] = acc[fm][fn][r];
    }
  }
}

extern "C" void kernel_launch(void* const* d_in, const int* in_sizes, int n_in,
                              void* d_out, int out_size, void* d_ws, size_t ws_size,
                              hipStream_t stream) {
  const float* hs   = (const float*)d_in[0];
  const float* in_w = (const float*)d_in[1];
  const float* cw   = (const float*)d_in[2];
  const float* cb   = (const float*)d_in[3];
  const float* xw   = (const float*)d_in[4];
  const float* dtw  = (const float*)d_in[5];
  const float* dtb  = (const float*)d_in[6];
  const float* alog = (const float*)d_in[7];
  const float* dsk  = (const float*)d_in[8];
  const float* ow   = (const float*)d_in[9];
  float* out = (float*)d_out;

  // ws layout (bytes), total ~185 MB
  char* ws = (char*)d_ws;
  unsigned short* xb  = (unsigned short*)(ws);                 // [M][384] bf16 25.17 MB (dead after conv)
  unsigned short* u16 = (unsigned short*)(ws + 25165824);      // [M][384] bf16 25.17 MB
  float* xdbl = (float*)(ws + 50331648);                       // [M][64]  fp32  8.39 MB
  float* dt   = (float*)(ws + 58720256);                       // [M][384] fp32 50.33 MB
  float* Pbuf = (float*)(ws + 109051904);                      // 25.17 MB (becomes h0)
  float* Sbuf = (float*)(ws + 134217728);                      // 25.17 MB
  unsigned short* zb  = (unsigned short*)(ws + 159383552);     // [M][384] bf16 25.17 MB
  unsigned short* wb  = (unsigned short*)(ws + 184549376);     // [768][192] bf16 294912 B
  unsigned short* wxb = (unsigned short*)(ws + 184844288);     // [64][384]  bf16  49152 B
  unsigned short* owb = (unsigned short*)(ws + 184893440);     // [192][384] bf16 147456 B
  unsigned short* yb  = xb;   // part3 output over dead xb

  // 0. weight casts/pads (one kernel)
  prep_k<<<576, 256, 0, stream>>>(in_w, xw, ow, wb, wxb, owb);
  // 1. in_proj (bf16 MFMA, XCD-swizzled, bf16 x|z outputs)
  gemm_in<<<dim3(6, 256), 256, 0, stream>>>(hs, wb, xb, zb);
  // 2. depthwise conv + SiLU (bf16 -> bf16)
  conv_silu_k<<<(MTOT * 48) / 256, 256, 0, stream>>>(xb, cw, cb, u16);
  // 3. x_proj (bf16 MFMA, fp32 out)
  xproj_mfma<<<MTOT / 64, 256, 0, stream>>>(u16, wxb, xdbl);
  // 4. dt_proj + softplus (double bias per reference)
  dtproj_k<<<(MTOT * 96) / 256, 256, 0, stream>>>(xdbl, dtw, dtb, dt);
  // 5. chunked selective scan
  scan_part1<<<dim3(NC, BATCH), 384, 0, stream>>>(dt, u16, xdbl, alog, Pbuf, Sbuf);
  scan_part2<<<(BATCH * DINNER * DSTATE) / 256, 256, 0, stream>>>(Pbuf, Sbuf);
  scan_part3<<<dim3(NC, BATCH), 384, 0, stream>>>(dt, u16, xdbl, alog, dsk, zb, Pbuf, yb);
  // 6. out_proj (bf16 MFMA, XCD-swizzled)
  gemm_out<<<dim3(3, 256), 256, 0, stream>>>(yb, owb, out);
}

// Round 8
// 222.886 us; speedup vs baseline: 16.0332x; 1.0524x over previous
//
#include <hip/hip_runtime.h>
#include <cmath>

#define BATCH 8
#define SEQLEN 4096
#define DMODEL 192
#define DINNER 384
#define DSTATE 16
#define DTRANK 12
#define XSTR 64            // padded x_dbl row stride (44 real cols)
#define MTOT (BATCH*SEQLEN)
#define CH 32              // scan chunk length
#define NC (SEQLEN/CH)     // 128 chunks

typedef __bf16 bf16x8 __attribute__((ext_vector_type(8)));
typedef float f32x4 __attribute__((ext_vector_type(4)));
typedef unsigned short us8 __attribute__((ext_vector_type(8)));

__device__ __forceinline__ float silu_f(float x) { return x / (1.f + __expf(-x)); }
__device__ __forceinline__ unsigned short f2bf(float f) {
  unsigned u = __float_as_uint(f);
  return (unsigned short)((u + 0x7FFF + ((u >> 16) & 1)) >> 16);   // RNE
}
__device__ __forceinline__ float bf2f(unsigned short b) {
  return __uint_as_float(((unsigned)b) << 16);
}

// a[n] = e1^(n+1), binary tree, depth 4
#define POW16(a, e1)                                                        \
  a[0] = (e1); a[1] = (e1) * (e1); a[2] = a[1] * (e1); a[3] = a[1] * a[1];  \
  a[4] = a[3] * (e1); a[5] = a[3] * a[1]; a[6] = a[3] * a[2];               \
  a[7] = a[3] * a[3]; a[8] = a[7] * (e1); a[9] = a[7] * a[1];               \
  a[10] = a[7] * a[2]; a[11] = a[7] * a[3]; a[12] = a[7] * a[4];            \
  a[13] = a[7] * a[5]; a[14] = a[7] * a[6]; a[15] = a[7] * a[7];

// single prep kernel: cast in_proj_w, pad+cast x_proj_w, cast out_proj_w
__global__ __launch_bounds__(256) void prep_k(const float* __restrict__ in_w,
                                              const float* __restrict__ xw,
                                              const float* __restrict__ ow,
                                              unsigned short* __restrict__ wb,
                                              unsigned short* __restrict__ wxb,
                                              unsigned short* __restrict__ owb) {
  const int i = blockIdx.x * 256 + threadIdx.x;
  if (i < 768 * DMODEL) wb[i] = f2bf(in_w[i]);
  if (i < XSTR * DINNER) wxb[i] = (i < 44 * DINNER) ? f2bf(xw[i]) : (unsigned short)0;
  if (i < DMODEL * DINNER) owb[i] = f2bf(ow[i]);
}

// in_proj: [M][768] = hs[M][192] @ in_w^T. BM=128 BN=128 BK=32, 4 waves (2x2),
// wave 64x64 = 4x4 frags. XCD-chunked swizzle: each XCD owns 32 m-panels x all
// 6 n-blocks -> A panel fetched by exactly one XCD L2. Outputs bf16 (x | z).
__global__ __launch_bounds__(256) void gemm_in(const float* __restrict__ hs,
                                               const unsigned short* __restrict__ wb,
                                               unsigned short* __restrict__ xb,
                                               unsigned short* __restrict__ zb) {
  __shared__ unsigned short Als[128 * 40];   // 80B rows
  __shared__ unsigned short Bls[128 * 40];
  const int tid = threadIdx.x;
  const int bid = blockIdx.y * 6 + blockIdx.x;        // 0..1535
  const int lid = (bid & 7) * 192 + (bid >> 3);       // bijective (1536%8==0)
  const int m0 = (lid / 6) * 128, n0 = (lid % 6) * 128;
  const int w = tid >> 6, l = tid & 63;
  const int wm = (w >> 1) * 64, wn = (w & 1) * 64;
  const int lr = l & 15, lk8 = (l >> 4) * 8;
  const int ar = tid >> 1, ag = (tid & 1) * 16;
  const float* Ap = hs + (size_t)(m0 + ar) * DMODEL + ag;
  const unsigned short* Wp = wb + (size_t)(n0 + ar) * DMODEL + ag;
  f32x4 acc[4][4];
#pragma unroll
  for (int i = 0; i < 4; i++)
#pragma unroll
    for (int j = 0; j < 4; j++) acc[i][j] = (f32x4){0.f, 0.f, 0.f, 0.f};
#pragma unroll
  for (int k0 = 0; k0 < DMODEL; k0 += 32) {
    float4 f0 = *(const float4*)(Ap + k0);
    float4 f1 = *(const float4*)(Ap + k0 + 4);
    float4 f2 = *(const float4*)(Ap + k0 + 8);
    float4 f3 = *(const float4*)(Ap + k0 + 12);
    us8 b0 = *(const us8*)(Wp + k0);
    us8 b1 = *(const us8*)(Wp + k0 + 8);
    us8 a0, a1;
    a0[0] = f2bf(f0.x); a0[1] = f2bf(f0.y); a0[2] = f2bf(f0.z); a0[3] = f2bf(f0.w);
    a0[4] = f2bf(f1.x); a0[5] = f2bf(f1.y); a0[6] = f2bf(f1.z); a0[7] = f2bf(f1.w);
    a1[0] = f2bf(f2.x); a1[1] = f2bf(f2.y); a1[2] = f2bf(f2.z); a1[3] = f2bf(f2.w);
    a1[4] = f2bf(f3.x); a1[5] = f2bf(f3.y); a1[6] = f2bf(f3.z); a1[7] = f2bf(f3.w);
    __syncthreads();
    *(us8*)(&Als[ar * 40 + ag]) = a0;
    *(us8*)(&Als[ar * 40 + ag + 8]) = a1;
    *(us8*)(&Bls[ar * 40 + ag]) = b0;
    *(us8*)(&Bls[ar * 40 + ag + 8]) = b1;
    __syncthreads();
    bf16x8 bfr[4];
#pragma unroll
    for (int fn = 0; fn < 4; fn++)
      bfr[fn] = *(const bf16x8*)(&Bls[(wn + fn * 16 + lr) * 40 + lk8]);
#pragma unroll
    for (int fm = 0; fm < 4; fm++) {
      bf16x8 af = *(const bf16x8*)(&Als[(wm + fm * 16 + lr) * 40 + lk8]);
#pragma unroll
      for (int fn = 0; fn < 4; fn++)
        acc[fm][fn] = __builtin_amdgcn_mfma_f32_16x16x32_bf16(af, bfr[fn], acc[fm][fn], 0, 0, 0);
    }
  }
  const int r0 = (l >> 4) * 4;   // C/D: col=lane&15, row=(lane>>4)*4+reg
  unsigned short* dst = (n0 < DINNER) ? xb : zb;
  const int cb0 = (n0 < DINNER) ? n0 : (n0 - DINNER);
#pragma unroll
  for (int fm = 0; fm < 4; fm++) {
    const size_t rowb = (size_t)(m0 + wm + fm * 16 + r0);
#pragma unroll
    for (int fn = 0; fn < 4; fn++) {
      const int col = cb0 + wn + fn * 16 + lr;
#pragma unroll
      for (int r = 0; r < 4; r++)
        dst[(rowb + r) * DINNER + col] = f2bf(acc[fm][fn][r]);
    }
  }
}

// depthwise conv (k=3, same-pad) + SiLU, bf16 in/out, 8 channels/thread
__global__ __launch_bounds__(256) void conv_silu_k(const unsigned short* __restrict__ xb,
                                                   const float* __restrict__ cw,
                                                   const float* __restrict__ cb,
                                                   unsigned short* __restrict__ u16) {
  __shared__ float cws[DINNER * 4];   // [0..3*384) = cw, [3*384..) = cb
  const int tid = threadIdx.x;
  for (int i = tid; i < DINNER * 4; i += 256)
    cws[i] = (i < DINNER * 3) ? cw[i] : cb[i - DINNER * 3];
  __syncthreads();
  const int idx = blockIdx.x * 256 + tid;
  const int d = (idx % 48) * 8;
  const int m = idx / 48;
  const int l = m % SEQLEN;
  const us8 c0 = *(const us8*)(xb + (size_t)m * DINNER + d);
  const bool hm = (l > 0), hp = (l < SEQLEN - 1);
  us8 cm = c0, cp = c0;
  if (hm) cm = *(const us8*)(xb + (size_t)(m - 1) * DINNER + d);
  if (hp) cp = *(const us8*)(xb + (size_t)(m + 1) * DINNER + d);
  us8 o;
#pragma unroll
  for (int j = 0; j < 8; j++) {
    const int dj = d + j;
    float s = cws[DINNER * 3 + dj] + cws[dj * 3 + 1] * bf2f(c0[j]);
    if (hm) s += cws[dj * 3 + 0] * bf2f(cm[j]);
    if (hp) s += cws[dj * 3 + 2] * bf2f(cp[j]);
    o[j] = f2bf(silu_f(s));
  }
  *(us8*)(u16 + (size_t)m * DINNER + d) = o;
}

// x_proj: xdbl[M][64] fp32 = u16[M][384] @ wxb[64][384]^T (bf16 MFMA, fp32 acc)
__global__ __launch_bounds__(256) void xproj_mfma(const unsigned short* __restrict__ u16,
                                                  const unsigned short* __restrict__ wxb,
                                                  float* __restrict__ xdbl) {
  __shared__ unsigned short Als[64 * 40];
  __shared__ unsigned short Bls[64 * 40];
  const int tid = threadIdx.x;
  const int m0 = blockIdx.x * 64;
  const int w = tid >> 6, l = tid & 63;
  const int wm = (w >> 1) * 32, wn = (w & 1) * 32;
  const int lr = l & 15, lk8 = (l >> 4) * 8;
  const int ar = tid >> 2, ag = (tid & 3) * 8;
  const unsigned short* Ap = u16 + (size_t)(m0 + ar) * DINNER + ag;
  const unsigned short* Wp = wxb + (size_t)ar * DINNER + ag;
  f32x4 acc[2][2];
#pragma unroll
  for (int i = 0; i < 2; i++)
#pragma unroll
    for (int j = 0; j < 2; j++) acc[i][j] = (f32x4){0.f, 0.f, 0.f, 0.f};
#pragma unroll
  for (int k0 = 0; k0 < DINNER; k0 += 32) {
    us8 a0 = *(const us8*)(Ap + k0);
    us8 b0 = *(const us8*)(Wp + k0);
    __syncthreads();
    *(us8*)(&Als[ar * 40 + ag]) = a0;
    *(us8*)(&Bls[ar * 40 + ag]) = b0;
    __syncthreads();
    bf16x8 bf0 = *(const bf16x8*)(&Bls[(wn + lr) * 40 + lk8]);
    bf16x8 bf1 = *(const bf16x8*)(&Bls[(wn + 16 + lr) * 40 + lk8]);
#pragma unroll
    for (int fm = 0; fm < 2; fm++) {
      bf16x8 af = *(const bf16x8*)(&Als[(wm + fm * 16 + lr) * 40 + lk8]);
      acc[fm][0] = __builtin_amdgcn_mfma_f32_16x16x32_bf16(af, bf0, acc[fm][0], 0, 0, 0);
      acc[fm][1] = __builtin_amdgcn_mfma_f32_16x16x32_bf16(af, bf1, acc[fm][1], 0, 0, 0);
    }
  }
  const int r0 = (l >> 4) * 4;
#pragma unroll
  for (int fm = 0; fm < 2; fm++) {
    const size_t rowb = (size_t)(m0 + wm + fm * 16 + r0);
#pragma unroll
    for (int fn = 0; fn < 2; fn++) {
      const int col = wn + fn * 16 + lr;
#pragma unroll
      for (int r = 0; r < 4; r++)
        xdbl[(rowb + r) * XSTR + col] = acc[fm][fn][r];
    }
  }
}

// dt[M][384] = softplus(x_dbl[:, :12] @ dt_proj_w^T + 2*dt_proj_b), 4 d/thread.
// Fast stable softplus: max(s,0) + log(1+exp(-|s|)) — v_exp_f32 + v_log_f32,
// no libm log1pf (which cost ~370 VALU ops/output per round-7 PMC).
__global__ __launch_bounds__(256) void dtproj_k(const float* __restrict__ xdbl,
                                                const float* __restrict__ dtw,
                                                const float* __restrict__ dtb,
                                                float* __restrict__ dt) {
  const int idx = blockIdx.x * 256 + threadIdx.x;
  const int q = (idx % 96) * 4;
  const size_t m = idx / 96;
  const float* xr = xdbl + m * XSTR;
  float xs[12];
  *(float4*)(xs) = *(const float4*)(xr);
  *(float4*)(xs + 4) = *(const float4*)(xr + 4);
  *(float4*)(xs + 8) = *(const float4*)(xr + 8);
  float4 o;
#pragma unroll
  for (int t = 0; t < 4; t++) {
    const int dd = q + t;
    const float* wr = dtw + dd * DTRANK;
    float s = 2.f * dtb[dd];
#pragma unroll
    for (int r = 0; r < DTRANK; r++) s = fmaf(xs[r], wr[r], s);
    ((float*)&o)[t] = fmaxf(s, 0.f) + __logf(1.f + __expf(-fabsf(s)));
  }
  *(float4*)(dt + m * DINNER + q) = o;
}

// ---- chunked parallel scan, thread-per-(b,d), 16 states in registers ----
__global__ __launch_bounds__(384, 6) void scan_part1(const float* __restrict__ dt,
                                                     const unsigned short* __restrict__ u16,
                                                     const float* __restrict__ xdbl,
                                                     const float* __restrict__ A_log,
                                                     float* __restrict__ Pbuf,
                                                     float* __restrict__ Sbuf) {
  __shared__ float Bs[CH][DSTATE];
  const int d = threadIdx.x;
  const int c = blockIdx.x, b = blockIdx.y;
  const size_t mbase = (size_t)b * SEQLEN + (size_t)c * CH;
  if (d < CH * 4) {
    const int r = d >> 2, q = d & 3;
    float4 v = *(const float4*)(xdbl + (mbase + r) * XSTR + DTRANK + q * 4);
    float* dst = &Bs[r][q * 4];
    dst[0] = v.x; dst[1] = v.y; dst[2] = v.z; dst[3] = v.w;
  }
  float Av[DSTATE];
#pragma unroll
  for (int q = 0; q < 4; q++) {
    float4 v = *(const float4*)(A_log + d * DSTATE + q * 4);
    Av[q * 4 + 0] = -__expf(v.x); Av[q * 4 + 1] = -__expf(v.y);
    Av[q * 4 + 2] = -__expf(v.z); Av[q * 4 + 3] = -__expf(v.w);
  }
  bool fastp = true;
#pragma unroll
  for (int n = 0; n < DSTATE; n++)
    fastp = fastp && (fabsf(Av[n] + (float)(n + 1)) < 1e-5f * (float)(n + 1));
  float h[DSTATE];
#pragma unroll
  for (int n = 0; n < DSTATE; n++) h[n] = 0.f;
  float dtsum = 0.f;
  __syncthreads();
  float dtv = dt[mbase * DINNER + d];
  float uv  = bf2f(u16[mbase * DINNER + d]);
  if (fastp) {
    for (int l = 0; l < CH; l++) {
      const int lp = (l + 1 < CH) ? (l + 1) : l;
      const float dtn = dt[(mbase + lp) * DINNER + d];
      const float un  = bf2f(u16[(mbase + lp) * DINNER + d]);
      const float du = dtv * uv;
      dtsum += dtv;
      float a[DSTATE];
      const float e1 = __expf(-dtv);
      POW16(a, e1)
#pragma unroll
      for (int n = 0; n < DSTATE; n++)
        h[n] = fmaf(a[n], h[n], du * Bs[l][n]);
      dtv = dtn; uv = un;
    }
  } else {
    for (int l = 0; l < CH; l++) {
      const int lp = (l + 1 < CH) ? (l + 1) : l;
      const float dtn = dt[(mbase + lp) * DINNER + d];
      const float un  = bf2f(u16[(mbase + lp) * DINNER + d]);
      const float du = dtv * uv;
      dtsum += dtv;
#pragma unroll
      for (int n = 0; n < DSTATE; n++) {
        const float a = __expf(dtv * Av[n]);
        h[n] = fmaf(a, h[n], du * Bs[l][n]);
      }
      dtv = dtn; uv = un;
    }
  }
  float P[DSTATE];
  if (fastp) {
    const float ep = __expf(-dtsum);
    POW16(P, ep)
  } else {
#pragma unroll
    for (int n = 0; n < DSTATE; n++) P[n] = __expf(dtsum * Av[n]);
  }
  float* Pp = Pbuf + ((size_t)(b * NC + c) * DINNER + d) * DSTATE;
  float* Sp = Sbuf + ((size_t)(b * NC + c) * DINNER + d) * DSTATE;
#pragma unroll
  for (int q = 0; q < 4; q++) {
    float4 pv, sv;
    pv.x = P[q * 4 + 0]; pv.y = P[q * 4 + 1]; pv.z = P[q * 4 + 2]; pv.w = P[q * 4 + 3];
    sv.x = h[q * 4 + 0]; sv.y = h[q * 4 + 1]; sv.z = h[q * 4 + 2]; sv.w = h[q * 4 + 3];
    *(float4*)(Pp + q * 4) = pv;
    *(float4*)(Sp + q * 4) = sv;
  }
}

__global__ __launch_bounds__(256) void scan_part2(float* __restrict__ Pbuf,
                                                  const float* __restrict__ Sbuf) {
  const int i = blockIdx.x * 256 + threadIdx.x;
  const int b = i / (DINNER * DSTATE);
  const int r = i % (DINNER * DSTATE);
  float h = 0.f;
  for (int c = 0; c < NC; c++) {
    const size_t idx = (size_t)(b * NC + c) * (DINNER * DSTATE) + r;
    const float p = Pbuf[idx], s = Sbuf[idx];
    Pbuf[idx] = h;
    h = fmaf(p, h, s);
  }
}

// Pass 3: re-run from h0; y = (h.C + D*u)*silu(z) emitted bf16 for out_proj.
__global__ __launch_bounds__(384, 6) void scan_part3(const float* __restrict__ dt,
                                                     const unsigned short* __restrict__ u16,
                                                     const float* __restrict__ xdbl,
                                                     const float* __restrict__ A_log,
                                                     const float* __restrict__ Dsk,
                                                     const unsigned short* __restrict__ zb,
                                                     const float* __restrict__ H0,
                                                     unsigned short* __restrict__ yb) {
  __shared__ float BC[CH][2 * DSTATE];
  const int d = threadIdx.x;
  const int c = blockIdx.x, b = blockIdx.y;
  const size_t mbase = (size_t)b * SEQLEN + (size_t)c * CH;
  for (int i = d; i < CH * 8; i += 384) {
    const int r = i >> 3, q = i & 7;
    float4 v = *(const float4*)(xdbl + (mbase + r) * XSTR + DTRANK + q * 4);
    float* dst = &BC[r][q * 4];
    dst[0] = v.x; dst[1] = v.y; dst[2] = v.z; dst[3] = v.w;
  }
  float Av[DSTATE];
#pragma unroll
  for (int q = 0; q < 4; q++) {
    float4 v = *(const float4*)(A_log + d * DSTATE + q * 4);
    Av[q * 4 + 0] = -__expf(v.x); Av[q * 4 + 1] = -__expf(v.y);
    Av[q * 4 + 2] = -__expf(v.z); Av[q * 4 + 3] = -__expf(v.w);
  }
  bool fastp = true;
#pragma unroll
  for (int n = 0; n < DSTATE; n++)
    fastp = fastp && (fabsf(Av[n] + (float)(n + 1)) < 1e-5f * (float)(n + 1));
  const float Dv = Dsk[d];
  float h[DSTATE];
  {
    const float* Hp = H0 + ((size_t)(b * NC + c) * DINNER + d) * DSTATE;
#pragma unroll
    for (int q = 0; q < 4; q++) {
      float4 v = *(const float4*)(Hp + q * 4);
      h[q * 4 + 0] = v.x; h[q * 4 + 1] = v.y; h[q * 4 + 2] = v.z; h[q * 4 + 3] = v.w;
    }
  }
  __syncthreads();
  float dtv = dt[mbase * DINNER + d];
  float uv  = bf2f(u16[mbase * DINNER + d]);
  float zv  = bf2f(zb[mbase * DINNER + d]);
  if (fastp) {
    for (int l = 0; l < CH; l++) {
      const int lp = (l + 1 < CH) ? (l + 1) : l;
      const float dtn = dt[(mbase + lp) * DINNER + d];
      const float un  = bf2f(u16[(mbase + lp) * DINNER + d]);
      const float zn  = bf2f(zb[(mbase + lp) * DINNER + d]);
      const float du = dtv * uv;
      float yacc = Dv * uv;
      float a[DSTATE];
      const float e1 = __expf(-dtv);
      POW16(a, e1)
#pragma unroll
      for (int n = 0; n < DSTATE; n++) {
        h[n] = fmaf(a[n], h[n], du * BC[l][n]);
        yacc = fmaf(h[n], BC[l][DSTATE + n], yacc);
      }
      yb[(mbase + l) * DINNER + d] = f2bf(yacc * silu_f(zv));
      dtv = dtn; uv = un; zv = zn;
    }
  } else {
    for (int l = 0; l < CH; l++) {
      const int lp = (l + 1 < CH) ? (l + 1) : l;
      const float dtn = dt[(mbase + lp) * DINNER + d];
      const float un  = bf2f(u16[(mbase + lp) * DINNER + d]);
      const float zn  = bf2f(zb[(mbase + lp) * DINNER + d]);
      const float du = dtv * uv;
      float yacc = Dv * uv;
#pragma unroll
      for (int n = 0; n < DSTATE; n++) {
        const float a = __expf(dtv * Av[n]);
        h[n] = fmaf(a, h[n], du * BC[l][n]);
        yacc = fmaf(h[n], BC[l][DSTATE + n], yacc);
      }
      yb[(mbase + l) * DINNER + d] = f2bf(yacc * silu_f(zv));
      dtv = dtn; uv = un; zv = zn;
    }
  }
}

// out_proj: out[M][192] fp32 = yb[M][384] @ ow^T. BM=128 BN=64 BK=32, XCD swizzle.
__global__ __launch_bounds__(256) void gemm_out(const unsigned short* __restrict__ yb,
                                                const unsigned short* __restrict__ owb,
                                                float* __restrict__ out) {
  __shared__ unsigned short Als[128 * 40];
  __shared__ unsigned short Bls[64 * 40];
  const int tid = threadIdx.x;
  const int bid = blockIdx.y * 3 + blockIdx.x;        // 0..767
  const int lid = (bid & 7) * 96 + (bid >> 3);        // bijective (768%8==0)
  const int m0 = (lid / 3) * 128, n0 = (lid % 3) * 64;
  const int w = tid >> 6, l = tid & 63;
  const int wm = (w >> 1) * 64, wn = (w & 1) * 32;
  const int lr = l & 15, lk8 = (l >> 4) * 8;
  const int ar = tid >> 1, ag = (tid & 1) * 16;
  const int br = tid >> 2, bg = (tid & 3) * 8;
  const unsigned short* Ap = yb + (size_t)(m0 + ar) * DINNER + ag;
  const unsigned short* Wp = owb + (size_t)(n0 + br) * DINNER + bg;
  f32x4 acc[4][2];
#pragma unroll
  for (int i = 0; i < 4; i++)
#pragma unroll
    for (int j = 0; j < 2; j++) acc[i][j] = (f32x4){0.f, 0.f, 0.f, 0.f};
#pragma unroll
  for (int k0 = 0; k0 < DINNER; k0 += 32) {
    us8 a0 = *(const us8*)(Ap + k0);
    us8 a1 = *(const us8*)(Ap + k0 + 8);
    us8 bv = *(const us8*)(Wp + k0);
    __syncthreads();
    *(us8*)(&Als[ar * 40 + ag]) = a0;
    *(us8*)(&Als[ar * 40 + ag + 8]) = a1;
    *(us8*)(&Bls[br * 40 + bg]) = bv;
    __syncthreads();
    bf16x8 b0 = *(const bf16x8*)(&Bls[(wn + lr) * 40 + lk8]);
    bf16x8 b1 = *(const bf16x8*)(&Bls[(wn + 16 + lr) * 40 + lk8]);
#pragma unroll
    for (int fm = 0; fm < 4; fm++) {
      bf16x8 af = *(const bf16x8*)(&Als[(wm + fm * 16 + lr) * 40 + lk8]);
      acc[fm][0] = __builtin_amdgcn_mfma_f32_16x16x32_bf16(af, b0, acc[fm][0], 0, 0, 0);
      acc[fm][1] = __builtin_amdgcn_mfma_f32_16x16x32_bf16(af, b1, acc[fm][1], 0, 0, 0);
    }
  }
  const int r0 = (l >> 4) * 4;
#pragma unroll
  for (int fm = 0; fm < 4; fm++) {
    const size_t rowb = (size_t)(m0 + wm + fm * 16 + r0);
#pragma unroll
    for (int fn = 0; fn < 2; fn++) {
      const int col = n0 + wn + fn * 16 + lr;
#pragma unroll
      for (int r = 0; r < 4; r++)
        out[(rowb + r) * DMODEL + col] = acc[fm][fn][r];
    }
  }
}

extern "C" void kernel_launch(void* const* d_in, const int* in_sizes, int n_in,
                              void* d_out, int out_size, void* d_ws, size_t ws_size,
                              hipStream_t stream) {
  const float* hs   = (const float*)d_in[0];
  const float* in_w = (const float*)d_in[1];
  const float* cw   = (const float*)d_in[2];
  const float* cb   = (const float*)d_in[3];
  const float* xw   = (const float*)d_in[4];
  const float* dtw  = (const float*)d_in[5];
  const float* dtb  = (const float*)d_in[6];
  const float* alog = (const float*)d_in[7];
  const float* dsk  = (const float*)d_in[8];
  const float* ow   = (const float*)d_in[9];
  float* out = (float*)d_out;

  // ws layout (bytes), total ~185 MB
  char* ws = (char*)d_ws;
  unsigned short* xb  = (unsigned short*)(ws);                 // [M][384] bf16 25.17 MB (dead after conv)
  unsigned short* u16 = (unsigned short*)(ws + 25165824);      // [M][384] bf16 25.17 MB
  float* xdbl = (float*)(ws + 50331648);                       // [M][64]  fp32  8.39 MB
  float* dt   = (float*)(ws + 58720256);                       // [M][384] fp32 50.33 MB
  float* Pbuf = (float*)(ws + 109051904);                      // 25.17 MB (becomes h0)
  float* Sbuf = (float*)(ws + 134217728);                      // 25.17 MB
  unsigned short* zb  = (unsigned short*)(ws + 159383552);     // [M][384] bf16 25.17 MB
  unsigned short* wb  = (unsigned short*)(ws + 184549376);     // [768][192] bf16 294912 B
  unsigned short* wxb = (unsigned short*)(ws + 184844288);     // [64][384]  bf16  49152 B
  unsigned short* owb = (unsigned short*)(ws + 184893440);     // [192][384] bf16 147456 B
  unsigned short* yb  = xb;   // part3 output over dead xb

  // 0. weight casts/pads (one kernel)
  prep_k<<<576, 256, 0, stream>>>(in_w, xw, ow, wb, wxb, owb);
  // 1. in_proj (bf16 MFMA, XCD-swizzled, bf16 x|z outputs)
  gemm_in<<<dim3(6, 256), 256, 0, stream>>>(hs, wb, xb, zb);
  // 2. depthwise conv + SiLU (bf16 -> bf16)
  conv_silu_k<<<(MTOT * 48) / 256, 256, 0, stream>>>(xb, cw, cb, u16);
  // 3. x_proj (bf16 MFMA, fp32 out)
  xproj_mfma<<<MTOT / 64, 256, 0, stream>>>(u16, wxb, xdbl);
  // 4. dt_proj + fast softplus (double bias per reference)
  dtproj_k<<<(MTOT * 96) / 256, 256, 0, stream>>>(xdbl, dtw, dtb, dt);
  // 5. chunked selective scan
  scan_part1<<<dim3(NC, BATCH), 384, 0, stream>>>(dt, u16, xdbl, alog, Pbuf, Sbuf);
  scan_part2<<<(BATCH * DINNER * DSTATE) / 256, 256, 0, stream>>>(Pbuf, Sbuf);
  scan_part3<<<dim3(NC, BATCH), 384, 0, stream>>>(dt, u16, xdbl, alog, dsk, zb, Pbuf, yb);
  // 6. out_proj (bf16 MFMA, XCD-swizzled)
  gemm_out<<<dim3(3, 256), 256, 0, stream>>>(yb, owb, out);
}

// Round 9
// 200.238 us; speedup vs baseline: 17.8467x; 1.1131x over previous
//
#include <hip/hip_runtime.h>
#include <cmath>

#define BATCH 8
#define SEQLEN 4096
#define DMODEL 192
#define DINNER 384
#define DSTATE 16
#define DTRANK 12
#define XSTR 64            // padded x_dbl row stride (44 real cols)
#define MTOT (BATCH*SEQLEN)
#define CH 32              // scan chunk length
#define NC (SEQLEN/CH)     // 128 chunks

typedef __bf16 bf16x8 __attribute__((ext_vector_type(8)));
typedef float f32x4 __attribute__((ext_vector_type(4)));
typedef unsigned short us8 __attribute__((ext_vector_type(8)));

__device__ __forceinline__ float fast_rcp(float x) { return __builtin_amdgcn_rcpf(x); }
__device__ __forceinline__ float silu_f(float x) { return x * fast_rcp(1.f + __expf(-x)); }
__device__ __forceinline__ unsigned short f2bf(float f) {
  unsigned u = __float_as_uint(f);
  return (unsigned short)((u + 0x7FFF + ((u >> 16) & 1)) >> 16);   // RNE
}
__device__ __forceinline__ float bf2f(unsigned short b) {
  return __uint_as_float(((unsigned)b) << 16);
}

// a[n] = e1^(n+1), binary tree, depth 4
#define POW16(a, e1)                                                        \
  a[0] = (e1); a[1] = (e1) * (e1); a[2] = a[1] * (e1); a[3] = a[1] * a[1];  \
  a[4] = a[3] * (e1); a[5] = a[3] * a[1]; a[6] = a[3] * a[2];               \
  a[7] = a[3] * a[3]; a[8] = a[7] * (e1); a[9] = a[7] * a[1];               \
  a[10] = a[7] * a[2]; a[11] = a[7] * a[3]; a[12] = a[7] * a[4];            \
  a[13] = a[7] * a[5]; a[14] = a[7] * a[6]; a[15] = a[7] * a[7];

// softplus pieces: dtv = softplus(s), e1 = exp(-dtv) = sigmoid(-s) via rcp
#define SOFTPLUS_E1(s, dtv, e1)                                             \
  { const float w_ = __expf(-fabsf(s));                                     \
    const float t_ = 1.f + w_;                                              \
    const float rq_ = fast_rcp(t_);                                         \
    dtv = fmaxf(s, 0.f) + __logf(t_);                                       \
    e1 = (s > 0.f) ? w_ * rq_ : rq_; }

// single prep kernel: cast in_proj_w, pad+cast x_proj_w, cast out_proj_w
__global__ __launch_bounds__(256) void prep_k(const float* __restrict__ in_w,
                                              const float* __restrict__ xw,
                                              const float* __restrict__ ow,
                                              unsigned short* __restrict__ wb,
                                              unsigned short* __restrict__ wxb,
                                              unsigned short* __restrict__ owb) {
  const int i = blockIdx.x * 256 + threadIdx.x;
  if (i < 768 * DMODEL) wb[i] = f2bf(in_w[i]);
  if (i < XSTR * DINNER) wxb[i] = (i < 44 * DINNER) ? f2bf(xw[i]) : (unsigned short)0;
  if (i < DMODEL * DINNER) owb[i] = f2bf(ow[i]);
}

// in_proj: [M][768] = hs[M][192] @ in_w^T. BM=128 BN=128 BK=32, XCD-chunked swizzle.
__global__ __launch_bounds__(256) void gemm_in(const float* __restrict__ hs,
                                               const unsigned short* __restrict__ wb,
                                               unsigned short* __restrict__ xb,
                                               unsigned short* __restrict__ zb) {
  __shared__ unsigned short Als[128 * 40];   // 80B rows
  __shared__ unsigned short Bls[128 * 40];
  const int tid = threadIdx.x;
  const int bid = blockIdx.y * 6 + blockIdx.x;        // 0..1535
  const int lid = (bid & 7) * 192 + (bid >> 3);       // bijective (1536%8==0)
  const int m0 = (lid / 6) * 128, n0 = (lid % 6) * 128;
  const int w = tid >> 6, l = tid & 63;
  const int wm = (w >> 1) * 64, wn = (w & 1) * 64;
  const int lr = l & 15, lk8 = (l >> 4) * 8;
  const int ar = tid >> 1, ag = (tid & 1) * 16;
  const float* Ap = hs + (size_t)(m0 + ar) * DMODEL + ag;
  const unsigned short* Wp = wb + (size_t)(n0 + ar) * DMODEL + ag;
  f32x4 acc[4][4];
#pragma unroll
  for (int i = 0; i < 4; i++)
#pragma unroll
    for (int j = 0; j < 4; j++) acc[i][j] = (f32x4){0.f, 0.f, 0.f, 0.f};
#pragma unroll
  for (int k0 = 0; k0 < DMODEL; k0 += 32) {
    float4 f0 = *(const float4*)(Ap + k0);
    float4 f1 = *(const float4*)(Ap + k0 + 4);
    float4 f2 = *(const float4*)(Ap + k0 + 8);
    float4 f3 = *(const float4*)(Ap + k0 + 12);
    us8 b0 = *(const us8*)(Wp + k0);
    us8 b1 = *(const us8*)(Wp + k0 + 8);
    us8 a0, a1;
    a0[0] = f2bf(f0.x); a0[1] = f2bf(f0.y); a0[2] = f2bf(f0.z); a0[3] = f2bf(f0.w);
    a0[4] = f2bf(f1.x); a0[5] = f2bf(f1.y); a0[6] = f2bf(f1.z); a0[7] = f2bf(f1.w);
    a1[0] = f2bf(f2.x); a1[1] = f2bf(f2.y); a1[2] = f2bf(f2.z); a1[3] = f2bf(f2.w);
    a1[4] = f2bf(f3.x); a1[5] = f2bf(f3.y); a1[6] = f2bf(f3.z); a1[7] = f2bf(f3.w);
    __syncthreads();
    *(us8*)(&Als[ar * 40 + ag]) = a0;
    *(us8*)(&Als[ar * 40 + ag + 8]) = a1;
    *(us8*)(&Bls[ar * 40 + ag]) = b0;
    *(us8*)(&Bls[ar * 40 + ag + 8]) = b1;
    __syncthreads();
    bf16x8 bfr[4];
#pragma unroll
    for (int fn = 0; fn < 4; fn++)
      bfr[fn] = *(const bf16x8*)(&Bls[(wn + fn * 16 + lr) * 40 + lk8]);
#pragma unroll
    for (int fm = 0; fm < 4; fm++) {
      bf16x8 af = *(const bf16x8*)(&Als[(wm + fm * 16 + lr) * 40 + lk8]);
#pragma unroll
      for (int fn = 0; fn < 4; fn++)
        acc[fm][fn] = __builtin_amdgcn_mfma_f32_16x16x32_bf16(af, bfr[fn], acc[fm][fn], 0, 0, 0);
    }
  }
  const int r0 = (l >> 4) * 4;   // C/D: col=lane&15, row=(lane>>4)*4+reg
  unsigned short* dst = (n0 < DINNER) ? xb : zb;
  const int cb0 = (n0 < DINNER) ? n0 : (n0 - DINNER);
#pragma unroll
  for (int fm = 0; fm < 4; fm++) {
    const size_t rowb = (size_t)(m0 + wm + fm * 16 + r0);
#pragma unroll
    for (int fn = 0; fn < 4; fn++) {
      const int col = cb0 + wn + fn * 16 + lr;
#pragma unroll
      for (int r = 0; r < 4; r++)
        dst[(rowb + r) * DINNER + col] = f2bf(acc[fm][fn][r]);
    }
  }
}

// depthwise conv (k=3, same-pad) + SiLU, bf16 in/out, 8 channels/thread
__global__ __launch_bounds__(256) void conv_silu_k(const unsigned short* __restrict__ xb,
                                                   const float* __restrict__ cw,
                                                   const float* __restrict__ cb,
                                                   unsigned short* __restrict__ u16) {
  __shared__ float cws[DINNER * 4];   // [0..3*384) = cw, [3*384..) = cb
  const int tid = threadIdx.x;
  for (int i = tid; i < DINNER * 4; i += 256)
    cws[i] = (i < DINNER * 3) ? cw[i] : cb[i - DINNER * 3];
  __syncthreads();
  const int idx = blockIdx.x * 256 + tid;
  const int d = (idx % 48) * 8;
  const int m = idx / 48;
  const int l = m % SEQLEN;
  const us8 c0 = *(const us8*)(xb + (size_t)m * DINNER + d);
  const bool hm = (l > 0), hp = (l < SEQLEN - 1);
  us8 cm = c0, cp = c0;
  if (hm) cm = *(const us8*)(xb + (size_t)(m - 1) * DINNER + d);
  if (hp) cp = *(const us8*)(xb + (size_t)(m + 1) * DINNER + d);
  us8 o;
#pragma unroll
  for (int j = 0; j < 8; j++) {
    const int dj = d + j;
    float s = cws[DINNER * 3 + dj] + cws[dj * 3 + 1] * bf2f(c0[j]);
    if (hm) s += cws[dj * 3 + 0] * bf2f(cm[j]);
    if (hp) s += cws[dj * 3 + 2] * bf2f(cp[j]);
    o[j] = f2bf(silu_f(s));
  }
  *(us8*)(u16 + (size_t)m * DINNER + d) = o;
}

// x_proj: xdbl[M][64] fp32 = u16[M][384] @ wxb[64][384]^T (bf16 MFMA, fp32 acc)
__global__ __launch_bounds__(256) void xproj_mfma(const unsigned short* __restrict__ u16,
                                                  const unsigned short* __restrict__ wxb,
                                                  float* __restrict__ xdbl) {
  __shared__ unsigned short Als[64 * 40];
  __shared__ unsigned short Bls[64 * 40];
  const int tid = threadIdx.x;
  const int m0 = blockIdx.x * 64;
  const int w = tid >> 6, l = tid & 63;
  const int wm = (w >> 1) * 32, wn = (w & 1) * 32;
  const int lr = l & 15, lk8 = (l >> 4) * 8;
  const int ar = tid >> 2, ag = (tid & 3) * 8;
  const unsigned short* Ap = u16 + (size_t)(m0 + ar) * DINNER + ag;
  const unsigned short* Wp = wxb + (size_t)ar * DINNER + ag;
  f32x4 acc[2][2];
#pragma unroll
  for (int i = 0; i < 2; i++)
#pragma unroll
    for (int j = 0; j < 2; j++) acc[i][j] = (f32x4){0.f, 0.f, 0.f, 0.f};
#pragma unroll
  for (int k0 = 0; k0 < DINNER; k0 += 32) {
    us8 a0 = *(const us8*)(Ap + k0);
    us8 b0 = *(const us8*)(Wp + k0);
    __syncthreads();
    *(us8*)(&Als[ar * 40 + ag]) = a0;
    *(us8*)(&Bls[ar * 40 + ag]) = b0;
    __syncthreads();
    bf16x8 bf0 = *(const bf16x8*)(&Bls[(wn + lr) * 40 + lk8]);
    bf16x8 bf1 = *(const bf16x8*)(&Bls[(wn + 16 + lr) * 40 + lk8]);
#pragma unroll
    for (int fm = 0; fm < 2; fm++) {
      bf16x8 af = *(const bf16x8*)(&Als[(wm + fm * 16 + lr) * 40 + lk8]);
      acc[fm][0] = __builtin_amdgcn_mfma_f32_16x16x32_bf16(af, bf0, acc[fm][0], 0, 0, 0);
      acc[fm][1] = __builtin_amdgcn_mfma_f32_16x16x32_bf16(af, bf1, acc[fm][1], 0, 0, 0);
    }
  }
  const int r0 = (l >> 4) * 4;
#pragma unroll
  for (int fm = 0; fm < 2; fm++) {
    const size_t rowb = (size_t)(m0 + wm + fm * 16 + r0);
#pragma unroll
    for (int fn = 0; fn < 2; fn++) {
      const int col = wn + fn * 16 + lr;
#pragma unroll
      for (int r = 0; r < 4; r++)
        xdbl[(rowb + r) * XSTR + col] = acc[fm][fn][r];
    }
  }
}

// ---- chunked parallel scan, thread-per-(b,d), 16 states in registers ----
// dt is FUSED: s = xdbl[:, :12] . dtw[d] + 2*dtb[d]; dtv = softplus(s);
// e1 = exp(-dtv) = sigmoid(-s) via rcp (no exp of dtv needed).
// Fast path (A_log = tile(log(1..16))): a[n] = e1^(n+1); P = (prod e1)^(n+1).
__global__ __launch_bounds__(384, 6) void scan_part1(const unsigned short* __restrict__ u16,
                                                     const float* __restrict__ xdbl,
                                                     const float* __restrict__ A_log,
                                                     const float* __restrict__ dtw,
                                                     const float* __restrict__ dtb,
                                                     float* __restrict__ Pbuf,
                                                     float* __restrict__ Sbuf) {
  __shared__ float XL[CH * 32];               // [l][0..11]=dt-cols, [l][12..27]=B
  const int d = threadIdx.x;
  const int c = blockIdx.x, b = blockIdx.y;
  const size_t mbase = (size_t)b * SEQLEN + (size_t)c * CH;
  if (d < CH * 7) {
    const int r = d / 7, q = d % 7;
    float4 v = *(const float4*)(xdbl + (mbase + r) * XSTR + q * 4);
    *(float4*)(&XL[r * 32 + q * 4]) = v;
  }
  float wr[DTRANK];
#pragma unroll
  for (int q = 0; q < 3; q++)
    *(float4*)(wr + q * 4) = *(const float4*)(dtw + d * DTRANK + q * 4);
  const float b2 = 2.f * dtb[d];
  bool fastp = true;
#pragma unroll
  for (int n = 0; n < DSTATE; n++)
    fastp = fastp && (fabsf(A_log[d * DSTATE + n] - __logf((float)(n + 1))) < 1e-5f);
  float h[DSTATE];
#pragma unroll
  for (int n = 0; n < DSTATE; n++) h[n] = 0.f;
  __syncthreads();
  float uv = bf2f(u16[mbase * DINNER + d]);
  float P[DSTATE];
  if (fastp) {
    float Pprod = 1.f;
    for (int l = 0; l < CH; l++) {
      const int lp = (l + 1 < CH) ? (l + 1) : l;
      const float un = bf2f(u16[(mbase + lp) * DINNER + d]);
      const float* Lr = &XL[l * 32];
      float s = b2;
#pragma unroll
      for (int r = 0; r < DTRANK; r++) s = fmaf(Lr[r], wr[r], s);
      float dtv, e1;
      SOFTPLUS_E1(s, dtv, e1)
      const float du = dtv * uv;
      Pprod *= e1;
      float a[DSTATE];
      POW16(a, e1)
#pragma unroll
      for (int n = 0; n < DSTATE; n++)
        h[n] = fmaf(a[n], h[n], du * Lr[12 + n]);
      uv = un;
    }
    POW16(P, Pprod)
  } else {
    float Av[DSTATE];
#pragma unroll
    for (int n = 0; n < DSTATE; n++) Av[n] = -__expf(A_log[d * DSTATE + n]);
    float dtsum = 0.f;
    for (int l = 0; l < CH; l++) {
      const int lp = (l + 1 < CH) ? (l + 1) : l;
      const float un = bf2f(u16[(mbase + lp) * DINNER + d]);
      const float* Lr = &XL[l * 32];
      float s = b2;
#pragma unroll
      for (int r = 0; r < DTRANK; r++) s = fmaf(Lr[r], wr[r], s);
      float dtv, e1;
      SOFTPLUS_E1(s, dtv, e1)
      (void)e1;
      const float du = dtv * uv;
      dtsum += dtv;
#pragma unroll
      for (int n = 0; n < DSTATE; n++)
        h[n] = fmaf(__expf(dtv * Av[n]), h[n], du * Lr[12 + n]);
      uv = un;
    }
#pragma unroll
    for (int n = 0; n < DSTATE; n++) P[n] = __expf(dtsum * Av[n]);
  }
  float* Pp = Pbuf + ((size_t)(b * NC + c) * DINNER + d) * DSTATE;
  float* Sp = Sbuf + ((size_t)(b * NC + c) * DINNER + d) * DSTATE;
#pragma unroll
  for (int q = 0; q < 4; q++) {
    float4 pv, sv;
    pv.x = P[q * 4 + 0]; pv.y = P[q * 4 + 1]; pv.z = P[q * 4 + 2]; pv.w = P[q * 4 + 3];
    sv.x = h[q * 4 + 0]; sv.y = h[q * 4 + 1]; sv.z = h[q * 4 + 2]; sv.w = h[q * 4 + 3];
    *(float4*)(Pp + q * 4) = pv;
    *(float4*)(Sp + q * 4) = sv;
  }
}

// Pass 2: combine across chunks. Unroll x8 with batched loads (16 in flight)
// to break the 128-deep serial latency chain.
__global__ __launch_bounds__(256) void scan_part2(float* __restrict__ Pbuf,
                                                  const float* __restrict__ Sbuf) {
  const int i = blockIdx.x * 256 + threadIdx.x;
  const int b = i / (DINNER * DSTATE);
  const int r = i % (DINNER * DSTATE);
  const size_t cs = DINNER * DSTATE;
  const size_t base = (size_t)b * NC * cs + r;
  float h = 0.f;
  for (int c0 = 0; c0 < NC; c0 += 8) {
    float pp[8], ss[8];
#pragma unroll
    for (int j = 0; j < 8; j++) {
      pp[j] = Pbuf[base + (size_t)(c0 + j) * cs];
      ss[j] = Sbuf[base + (size_t)(c0 + j) * cs];
    }
#pragma unroll
    for (int j = 0; j < 8; j++) {
      Pbuf[base + (size_t)(c0 + j) * cs] = h;
      h = fmaf(pp[j], h, ss[j]);
    }
  }
}

// Pass 3: re-run from h0; y = (h.C + D*u)*silu(z) emitted bf16 for out_proj.
__global__ __launch_bounds__(384, 6) void scan_part3(const unsigned short* __restrict__ u16,
                                                     const float* __restrict__ xdbl,
                                                     const float* __restrict__ A_log,
                                                     const float* __restrict__ dtw,
                                                     const float* __restrict__ dtb,
                                                     const float* __restrict__ Dsk,
                                                     const unsigned short* __restrict__ zb,
                                                     const float* __restrict__ H0,
                                                     unsigned short* __restrict__ yb) {
  __shared__ float XL[CH * 48];   // [l][0..11]=dt-cols, [12..27]=B, [28..43]=C
  const int d = threadIdx.x;
  const int c = blockIdx.x, b = blockIdx.y;
  const size_t mbase = (size_t)b * SEQLEN + (size_t)c * CH;
  if (d < CH * 11) {
    const int r = d / 11, q = d % 11;
    float4 v = *(const float4*)(xdbl + (mbase + r) * XSTR + q * 4);
    *(float4*)(&XL[r * 48 + q * 4]) = v;
  }
  float wr[DTRANK];
#pragma unroll
  for (int q = 0; q < 3; q++)
    *(float4*)(wr + q * 4) = *(const float4*)(dtw + d * DTRANK + q * 4);
  const float b2 = 2.f * dtb[d];
  bool fastp = true;
#pragma unroll
  for (int n = 0; n < DSTATE; n++)
    fastp = fastp && (fabsf(A_log[d * DSTATE + n] - __logf((float)(n + 1))) < 1e-5f);
  const float Dv = Dsk[d];
  float h[DSTATE];
  {
    const float* Hp = H0 + ((size_t)(b * NC + c) * DINNER + d) * DSTATE;
#pragma unroll
    for (int q = 0; q < 4; q++) {
      float4 v = *(const float4*)(Hp + q * 4);
      h[q * 4 + 0] = v.x; h[q * 4 + 1] = v.y; h[q * 4 + 2] = v.z; h[q * 4 + 3] = v.w;
    }
  }
  __syncthreads();
  float uv = bf2f(u16[mbase * DINNER + d]);
  float zv = bf2f(zb[mbase * DINNER + d]);
  if (fastp) {
    for (int l = 0; l < CH; l++) {
      const int lp = (l + 1 < CH) ? (l + 1) : l;
      const float un = bf2f(u16[(mbase + lp) * DINNER + d]);
      const float zn = bf2f(zb[(mbase + lp) * DINNER + d]);
      const float* Lr = &XL[l * 48];
      float s = b2;
#pragma unroll
      for (int r = 0; r < DTRANK; r++) s = fmaf(Lr[r], wr[r], s);
      float dtv, e1;
      SOFTPLUS_E1(s, dtv, e1)
      const float du = dtv * uv;
      float a[DSTATE];
      POW16(a, e1)
      float y0 = Dv * uv, y1 = 0.f, y2 = 0.f, y3 = 0.f;
#pragma unroll
      for (int n = 0; n < DSTATE; n += 4) {
        h[n + 0] = fmaf(a[n + 0], h[n + 0], du * Lr[12 + n + 0]);
        h[n + 1] = fmaf(a[n + 1], h[n + 1], du * Lr[12 + n + 1]);
        h[n + 2] = fmaf(a[n + 2], h[n + 2], du * Lr[12 + n + 2]);
        h[n + 3] = fmaf(a[n + 3], h[n + 3], du * Lr[12 + n + 3]);
        y0 = fmaf(h[n + 0], Lr[28 + n + 0], y0);
        y1 = fmaf(h[n + 1], Lr[28 + n + 1], y1);
        y2 = fmaf(h[n + 2], Lr[28 + n + 2], y2);
        y3 = fmaf(h[n + 3], Lr[28 + n + 3], y3);
      }
      const float yacc = (y0 + y1) + (y2 + y3);
      yb[(mbase + l) * DINNER + d] = f2bf(yacc * silu_f(zv));
      uv = un; zv = zn;
    }
  } else {
    float Av[DSTATE];
#pragma unroll
    for (int n = 0; n < DSTATE; n++) Av[n] = -__expf(A_log[d * DSTATE + n]);
    for (int l = 0; l < CH; l++) {
      const int lp = (l + 1 < CH) ? (l + 1) : l;
      const float un = bf2f(u16[(mbase + lp) * DINNER + d]);
      const float zn = bf2f(zb[(mbase + lp) * DINNER + d]);
      const float* Lr = &XL[l * 48];
      float s = b2;
#pragma unroll
      for (int r = 0; r < DTRANK; r++) s = fmaf(Lr[r], wr[r], s);
      float dtv, e1;
      SOFTPLUS_E1(s, dtv, e1)
      (void)e1;
      const float du = dtv * uv;
      float yacc = Dv * uv;
#pragma unroll
      for (int n = 0; n < DSTATE; n++) {
        h[n] = fmaf(__expf(dtv * Av[n]), h[n], du * Lr[12 + n]);
        yacc = fmaf(h[n], Lr[28 + n], yacc);
      }
      yb[(mbase + l) * DINNER + d] = f2bf(yacc * silu_f(zv));
      uv = un; zv = zn;
    }
  }
}

// out_proj: out[M][192] fp32 = yb[M][384] @ ow^T. BM=128 BN=64 BK=32, XCD swizzle.
__global__ __launch_bounds__(256) void gemm_out(const unsigned short* __restrict__ yb,
                                                const unsigned short* __restrict__ owb,
                                                float* __restrict__ out) {
  __shared__ unsigned short Als[128 * 40];
  __shared__ unsigned short Bls[64 * 40];
  const int tid = threadIdx.x;
  const int bid = blockIdx.y * 3 + blockIdx.x;        // 0..767
  const int lid = (bid & 7) * 96 + (bid >> 3);        // bijective (768%8==0)
  const int m0 = (lid / 3) * 128, n0 = (lid % 3) * 64;
  const int w = tid >> 6, l = tid & 63;
  const int wm = (w >> 1) * 64, wn = (w & 1) * 32;
  const int lr = l & 15, lk8 = (l >> 4) * 8;
  const int ar = tid >> 1, ag = (tid & 1) * 16;
  const int br = tid >> 2, bg = (tid & 3) * 8;
  const unsigned short* Ap = yb + (size_t)(m0 + ar) * DINNER + ag;
  const unsigned short* Wp = owb + (size_t)(n0 + br) * DINNER + bg;
  f32x4 acc[4][2];
#pragma unroll
  for (int i = 0; i < 4; i++)
#pragma unroll
    for (int j = 0; j < 2; j++) acc[i][j] = (f32x4){0.f, 0.f, 0.f, 0.f};
#pragma unroll
  for (int k0 = 0; k0 < DINNER; k0 += 32) {
    us8 a0 = *(const us8*)(Ap + k0);
    us8 a1 = *(const us8*)(Ap + k0 + 8);
    us8 bv = *(const us8*)(Wp + k0);
    __syncthreads();
    *(us8*)(&Als[ar * 40 + ag]) = a0;
    *(us8*)(&Als[ar * 40 + ag + 8]) = a1;
    *(us8*)(&Bls[br * 40 + bg]) = bv;
    __syncthreads();
    bf16x8 b0 = *(const bf16x8*)(&Bls[(wn + lr) * 40 + lk8]);
    bf16x8 b1 = *(const bf16x8*)(&Bls[(wn + 16 + lr) * 40 + lk8]);
#pragma unroll
    for (int fm = 0; fm < 4; fm++) {
      bf16x8 af = *(const bf16x8*)(&Als[(wm + fm * 16 + lr) * 40 + lk8]);
      acc[fm][0] = __builtin_amdgcn_mfma_f32_16x16x32_bf16(af, b0, acc[fm][0], 0, 0, 0);
      acc[fm][1] = __builtin_amdgcn_mfma_f32_16x16x32_bf16(af, b1, acc[fm][1], 0, 0, 0);
    }
  }
  const int r0 = (l >> 4) * 4;
#pragma unroll
  for (int fm = 0; fm < 4; fm++) {
    const size_t rowb = (size_t)(m0 + wm + fm * 16 + r0);
#pragma unroll
    for (int fn = 0; fn < 2; fn++) {
      const int col = n0 + wn + fn * 16 + lr;
#pragma unroll
      for (int r = 0; r < 4; r++)
        out[(rowb + r) * DMODEL + col] = acc[fm][fn][r];
    }
  }
}

extern "C" void kernel_launch(void* const* d_in, const int* in_sizes, int n_in,
                              void* d_out, int out_size, void* d_ws, size_t ws_size,
                              hipStream_t stream) {
  const float* hs   = (const float*)d_in[0];
  const float* in_w = (const float*)d_in[1];
  const float* cw   = (const float*)d_in[2];
  const float* cb   = (const float*)d_in[3];
  const float* xw   = (const float*)d_in[4];
  const float* dtw  = (const float*)d_in[5];
  const float* dtb  = (const float*)d_in[6];
  const float* alog = (const float*)d_in[7];
  const float* dsk  = (const float*)d_in[8];
  const float* ow   = (const float*)d_in[9];
  float* out = (float*)d_out;

  // ws layout (bytes), total ~135 MB (dt buffer eliminated)
  char* ws = (char*)d_ws;
  unsigned short* xb  = (unsigned short*)(ws);                 // [M][384] bf16 25.17 MB (dead after conv)
  unsigned short* u16 = (unsigned short*)(ws + 25165824);      // [M][384] bf16 25.17 MB
  float* xdbl = (float*)(ws + 50331648);                       // [M][64]  fp32  8.39 MB
  float* Pbuf = (float*)(ws + 58720256);                       // 25.17 MB (becomes h0)
  float* Sbuf = (float*)(ws + 83886080);                       // 25.17 MB
  unsigned short* zb  = (unsigned short*)(ws + 109051904);     // [M][384] bf16 25.17 MB
  unsigned short* wb  = (unsigned short*)(ws + 134217728);     // [768][192] bf16 294912 B
  unsigned short* wxb = (unsigned short*)(ws + 134512640);     // [64][384]  bf16  49152 B
  unsigned short* owb = (unsigned short*)(ws + 134561792);     // [192][384] bf16 147456 B
  unsigned short* yb  = xb;   // part3 output over dead xb

  // 0. weight casts/pads (one kernel)
  prep_k<<<576, 256, 0, stream>>>(in_w, xw, ow, wb, wxb, owb);
  // 1. in_proj (bf16 MFMA, XCD-swizzled, bf16 x|z outputs)
  gemm_in<<<dim3(6, 256), 256, 0, stream>>>(hs, wb, xb, zb);
  // 2. depthwise conv + SiLU (bf16 -> bf16)
  conv_silu_k<<<(MTOT * 48) / 256, 256, 0, stream>>>(xb, cw, cb, u16);
  // 3. x_proj (bf16 MFMA, fp32 out)
  xproj_mfma<<<MTOT / 64, 256, 0, stream>>>(u16, wxb, xdbl);
  // 4+5. chunked selective scan with FUSED dt_proj+softplus (double bias per ref)
  scan_part1<<<dim3(NC, BATCH), 384, 0, stream>>>(u16, xdbl, alog, dtw, dtb, Pbuf, Sbuf);
  scan_part2<<<(BATCH * DINNER * DSTATE) / 256, 256, 0, stream>>>(Pbuf, Sbuf);
  scan_part3<<<dim3(NC, BATCH), 384, 0, stream>>>(u16, xdbl, alog, dtw, dtb, dsk, zb, Pbuf, yb);
  // 6. out_proj (bf16 MFMA, XCD-swizzled)
  gemm_out<<<dim3(3, 256), 256, 0, stream>>>(yb, owb, out);
}